// Round 1
// baseline (1031.562 us; speedup 1.0000x reference)
//
#include <hip/hip_runtime.h>

typedef unsigned short ushort_t;
typedef __bf16 bf16x8 __attribute__((ext_vector_type(8)));
typedef float f32x4 __attribute__((ext_vector_type(4)));

#define BB 4
#define MM 2048
#define NN 2048
#define DD 256

__device__ __forceinline__ ushort_t f2bf(float f) {
    unsigned int u = __float_as_uint(f);
    unsigned int r = (u + 0x7fffu + ((u >> 16) & 1u)) >> 16;
    return (ushort_t)r;
}
__device__ __forceinline__ float bf2f(ushort_t u) {
    return __uint_as_float(((unsigned int)u) << 16);
}
__device__ __forceinline__ float wredsum(float v) {
    for (int o = 32; o; o >>= 1) v += __shfl_xor(v, o, 64);
    return v;
}
__device__ __forceinline__ float wredmax(float v) {
    for (int o = 32; o; o >>= 1) v = fmaxf(v, __shfl_xor(v, o, 64));
    return v;
}
__device__ __forceinline__ float logsig(float z) {
    return (z >= 0.f) ? -log1pf(expf(-z)) : (z - log1pf(expf(z)));
}

// ---------------- weight prep ----------------
// Wov = Wo @ Wv (256x256), bvo = Wo@bv + bo
__global__ void k_wov(const float* __restrict__ Wo, const float* __restrict__ Wv,
                      const float* __restrict__ bvv, const float* __restrict__ bo,
                      ushort_t* __restrict__ Wovb, float* __restrict__ bvo) {
    int o = blockIdx.x, k = threadIdx.x;
    float s = 0.f;
    for (int j = 0; j < 256; ++j) s += Wo[o * 256 + j] * Wv[j * 256 + k];
    Wovb[o * 256 + k] = f2bf(s);
    float pb = Wo[o * 256 + k] * bvv[k];
    pb = wredsum(pb);
    __shared__ float sh[4];
    if ((k & 63) == 0) sh[k >> 6] = pb;
    __syncthreads();
    if (k == 0) bvo[o] = sh[0] + sh[1] + sh[2] + sh[3] + bo[o];
}

__global__ void k_cast_flat(const float* __restrict__ src, ushort_t* __restrict__ dst, int n) {
    int i = blockIdx.x * 256 + threadIdx.x;
    if (i < n) dst[i] = f2bf(src[i]);
}

// x (R,256) fp32 -> cat (R,512) bf16 at cols [0,256)
__global__ void k_cast_x(const float* __restrict__ src, ushort_t* __restrict__ dst) {
    long i = (long)blockIdx.x * 256 + threadIdx.x;  // < 8192*256
    long r = i >> 8;
    int c = (int)(i & 255);
    dst[r * 512 + c] = f2bf(src[i]);
}

// ---------------- row LSE (axis=-1) ----------------
__global__ void k_rowlse(const float* __restrict__ src, int ld, long bstride,
                         float* __restrict__ out) {
    int blk = blockIdx.x;
    int b = blk >> 11, m = blk & 2047;
    const float* p = src + (long)b * bstride + (long)m * ld;
    int t = threadIdx.x;
    float v[8];
    float mx = -3.4e38f;
#pragma unroll
    for (int i = 0; i < 8; ++i) { v[i] = p[i * 256 + t]; mx = fmaxf(mx, v[i]); }
    mx = wredmax(mx);
    __shared__ float sh[4];
    if ((t & 63) == 0) sh[t >> 6] = mx;
    __syncthreads();
    mx = fmaxf(fmaxf(sh[0], sh[1]), fmaxf(sh[2], sh[3]));
    float s = 0.f;
#pragma unroll
    for (int i = 0; i < 8; ++i) s += expf(v[i] - mx);
    s = wredsum(s);
    __shared__ float sh2[4];
    if ((t & 63) == 0) sh2[t >> 6] = s;
    __syncthreads();
    if (t == 0) out[blk] = mx + logf(sh2[0] + sh2[1] + sh2[2] + sh2[3]);
}

// ---------------- column LSE (axis=1), chunked online ----------------
__global__ void k_colpart(const float* __restrict__ src, int ld, long bstride,
                          float* __restrict__ pm, float* __restrict__ ps) {
    int b = blockIdx.z;
    int n = blockIdx.x * 256 + threadIdx.x;
    int mstart = blockIdx.y * 256;
    const float* p = src + (long)b * bstride + n;
    float mx = -3.4e38f, s = 0.f;
    for (int mm = 0; mm < 256; ++mm) {
        float v = p[(long)(mstart + mm) * ld];
        if (v > mx) { s = s * expf(mx - v) + 1.f; mx = v; }
        else s += expf(v - mx);
    }
    int idx = (b * 8 + blockIdx.y) * 2048 + n;
    pm[idx] = mx; ps[idx] = s;
}

__global__ void k_colcomb(const float* __restrict__ pm, const float* __restrict__ ps,
                          float* __restrict__ out) {
    int idx = blockIdx.x * 256 + threadIdx.x;  // 8192
    int b = idx >> 11, n = idx & 2047;
    float mx = -3.4e38f;
#pragma unroll
    for (int c = 0; c < 8; ++c) mx = fmaxf(mx, pm[(b * 8 + c) * 2048 + n]);
    float s = 0.f;
#pragma unroll
    for (int c = 0; c < 8; ++c) s += ps[(b * 8 + c) * 2048 + n] * expf(pm[(b * 8 + c) * 2048 + n] - mx);
    out[idx] = mx + logf(s);
}

// ---------------- materialize A01 (B,M,N) bf16 and At10 (B,N,M) bf16 ----------------
__global__ void k_mat(const float* __restrict__ adj, const float* __restrict__ rlse,
                      const float* __restrict__ clse, ushort_t* __restrict__ A01,
                      ushort_t* __restrict__ At10) {
    int b = blockIdx.z;
    int n0 = blockIdx.x * 64, m0 = blockIdx.y * 64;
    __shared__ ushort_t T[64][72];
    int t = threadIdx.x;
    int r = t >> 4, cq = t & 15;
    const float* base = adj + ((long)b * 2048 + m0) * 2048 + n0;
#pragma unroll
    for (int p = 0; p < 4; ++p) {
        int row = p * 16 + r;
        float4 v = *(const float4*)(base + (long)row * 2048 + cq * 4);
        float vf[4] = {v.x, v.y, v.z, v.w};
        float rl = rlse[b * 2048 + m0 + row];
        ushort_t e[4];
#pragma unroll
        for (int j = 0; j < 4; ++j) e[j] = f2bf(expf(vf[j] - rl));
        uint2 o;
        o.x = (unsigned)e[0] | ((unsigned)e[1] << 16);
        o.y = (unsigned)e[2] | ((unsigned)e[3] << 16);
        *(uint2*)&A01[((long)b * 2048 + m0 + row) * 2048 + n0 + cq * 4] = o;
#pragma unroll
        for (int j = 0; j < 4; ++j) {
            float cl = clse[b * 2048 + n0 + cq * 4 + j];
            T[cq * 4 + j][row] = f2bf(expf(vf[j] - cl));
        }
    }
    __syncthreads();
#pragma unroll
    for (int p = 0; p < 4; ++p) {
        int rn = p * 16 + r;
        uint2 o;
        o.x = (unsigned)T[rn][cq * 4 + 0] | ((unsigned)T[rn][cq * 4 + 1] << 16);
        o.y = (unsigned)T[rn][cq * 4 + 2] | ((unsigned)T[rn][cq * 4 + 3] << 16);
        *(uint2*)&At10[((long)b * 2048 + n0 + rn) * 2048 + m0 + cq * 4] = o;
    }
}

// ---------------- bf16 transpose (B,2048,256) -> (B,256,2048) ----------------
__global__ void k_tr(const ushort_t* __restrict__ src, ushort_t* __restrict__ dst) {
    int b = blockIdx.z;
    int c0 = blockIdx.x * 64, r0 = blockIdx.y * 64;
    const ushort_t* s = src + (long)b * 524288;
    ushort_t* d = dst + (long)b * 524288;
    __shared__ ushort_t T[64][68];
    int t = threadIdx.x;
    int ir = t >> 4, jc = t & 15;
#pragma unroll
    for (int p = 0; p < 4; ++p) {
        int row = p * 16 + ir;
        uint2 v = *(const uint2*)&s[(long)(r0 + row) * 256 + c0 + jc * 4];
        T[jc * 4 + 0][row] = (ushort_t)(v.x & 0xffff);
        T[jc * 4 + 1][row] = (ushort_t)(v.x >> 16);
        T[jc * 4 + 2][row] = (ushort_t)(v.y & 0xffff);
        T[jc * 4 + 3][row] = (ushort_t)(v.y >> 16);
    }
    __syncthreads();
#pragma unroll
    for (int p = 0; p < 4; ++p) {
        int crow = p * 16 + ir;
        uint2 o;
        o.x = (unsigned)T[crow][jc * 4 + 0] | ((unsigned)T[crow][jc * 4 + 1] << 16);
        o.y = (unsigned)T[crow][jc * 4 + 2] | ((unsigned)T[crow][jc * 4 + 3] << 16);
        *(uint2*)&d[(long)(c0 + crow) * 2048 + r0 + jc * 4] = o;
    }
}

// ---------------- MFMA GEMM: C[b,r,c] = sum_k A[b,r,k] * Bt[b,c,k] ----------------
// 128x128 tile, BK=64, 4 waves of 64x64, 16x16x32 bf16 MFMA.
// LDS layout: chunk (8 bf16) of (row, kc) at offset ((kc*130)+row)*8 shorts.
template <class Epi>
__global__ __launch_bounds__(256, 2) void gemm_bt(const ushort_t* __restrict__ A, long sA, int lda,
                                                  const ushort_t* __restrict__ Bt, long sB, int ldb,
                                                  int K, Epi epi) {
    __shared__ ushort_t lA[8 * 130 * 8];
    __shared__ ushort_t lB[8 * 130 * 8];
    const int b = blockIdx.z;
    const int m0 = blockIdx.x * 128, n0 = blockIdx.y * 128;
    const ushort_t* Ab = A + (long)b * sA;
    const ushort_t* Bb = Bt + (long)b * sB;
    const int t = threadIdx.x;
    const int lane = t & 63, wave = t >> 6;
    const int wm = (wave & 1) * 64, wn = (wave >> 1) * 64;
    const int q = lane >> 4, lm = lane & 15;

    const int4* pa[4];
    const int4* pb[4];
    int arow[4], akc[4];
#pragma unroll
    for (int i = 0; i < 4; ++i) {
        int c = i * 256 + t;
        arow[i] = c >> 3;
        akc[i] = c & 7;
        pa[i] = (const int4*)(Ab + (long)(m0 + arow[i]) * lda + akc[i] * 8);
        pb[i] = (const int4*)(Bb + (long)(n0 + arow[i]) * ldb + akc[i] * 8);
    }
    f32x4 zero = {0.f, 0.f, 0.f, 0.f};
    f32x4 acc[4][4];
#pragma unroll
    for (int mi = 0; mi < 4; ++mi)
#pragma unroll
        for (int ni = 0; ni < 4; ++ni) acc[mi][ni] = zero;

    int4 ra[4], rb[4];
#pragma unroll
    for (int i = 0; i < 4; ++i) { ra[i] = pa[i][0]; rb[i] = pb[i][0]; }

    const int nkt = K >> 6;
    for (int kt = 0; kt < nkt; ++kt) {
        __syncthreads();
#pragma unroll
        for (int i = 0; i < 4; ++i) {
            *(int4*)&lA[(akc[i] * 130 + arow[i]) * 8] = ra[i];
            *(int4*)&lB[(akc[i] * 130 + arow[i]) * 8] = rb[i];
        }
        __syncthreads();
        if (kt + 1 < nkt) {
#pragma unroll
            for (int i = 0; i < 4; ++i) { ra[i] = pa[i][(kt + 1) * 8]; rb[i] = pb[i][(kt + 1) * 8]; }
        }
#pragma unroll
        for (int kk = 0; kk < 2; ++kk) {
            bf16x8 af[4], bfr[4];
#pragma unroll
            for (int mi = 0; mi < 4; ++mi)
                af[mi] = *(const bf16x8*)&lA[((kk * 4 + q) * 130 + wm + mi * 16 + lm) * 8];
#pragma unroll
            for (int ni = 0; ni < 4; ++ni)
                bfr[ni] = *(const bf16x8*)&lB[((kk * 4 + q) * 130 + wn + ni * 16 + lm) * 8];
#pragma unroll
            for (int mi = 0; mi < 4; ++mi)
#pragma unroll
                for (int ni = 0; ni < 4; ++ni)
                    acc[mi][ni] = __builtin_amdgcn_mfma_f32_16x16x32_bf16(af[mi], bfr[ni], acc[mi][ni], 0, 0, 0);
        }
    }
#pragma unroll
    for (int mi = 0; mi < 4; ++mi)
#pragma unroll
        for (int ni = 0; ni < 4; ++ni)
#pragma unroll
            for (int r2 = 0; r2 < 4; ++r2) {
                int row = m0 + wm + mi * 16 + q * 4 + r2;
                int col = n0 + wn + ni * 16 + lm;
                epi(b, row, col, acc[mi][ni][r2]);
            }
}

// Epilogues
struct EpiB16 {  // row-major bf16 with bias: dst[r*256+c]
    ushort_t* dst; const float* bias;
    __device__ void operator()(int b, int r, int c, float v) const {
        dst[(long)r * 256 + c] = f2bf(v + bias[c]);
    }
};
struct EpiCat {  // bf16 into cat[b][r][256+c], ld=512
    ushort_t* dst;
    __device__ void operator()(int b, int r, int c, float v) const {
        dst[((long)b * 2048 + r) * 512 + 256 + c] = f2bf(v);
    }
};
struct EpiH {  // fp32 + bias, ld=512
    float* dst; const float* bias;
    __device__ void operator()(int b, int r, int c, float v) const {
        dst[(long)r * 512 + c] = v + bias[c];
    }
};
struct EpiD {  // bf16 = v + bias + residual
    ushort_t* dst; const float* bias; const float* resid;
    __device__ void operator()(int b, int r, int c, float v) const {
        dst[(long)r * 256 + c] = f2bf(v + bias[c] + resid[(long)r * 256 + c]);
    }
};
struct EpiMd {  // bf16 = (v+bias)*0.25
    ushort_t* dst; const float* bias;
    __device__ void operator()(int b, int r, int c, float v) const {
        dst[(long)r * 256 + c] = f2bf((v + bias[c]) * 0.25f);
    }
};
struct EpiSim {  // fp32 into scores area, ld=2049
    float* dst;
    __device__ void operator()(int b, int r, int c, float v) const {
        dst[(long)b * 4198401 + (long)r * 2049 + c] = v;
    }
};

// ---------------- LN + GELU ----------------
__global__ void k_ln(const float* __restrict__ h, const float* __restrict__ lng,
                     const float* __restrict__ lnb, ushort_t* __restrict__ out) {
    int row = blockIdx.x;
    int t = threadIdx.x;
    const float* p = h + (long)row * 512;
    float a = p[t], c = p[t + 256];
    float s = wredsum(a + c);
    __shared__ float sh[4];
    if ((t & 63) == 0) sh[t >> 6] = s;
    __syncthreads();
    float mean = (sh[0] + sh[1] + sh[2] + sh[3]) * (1.f / 512.f);
    float da = a - mean, dc = c - mean;
    float s2 = wredsum(da * da + dc * dc);
    __shared__ float sh2[4];
    if ((t & 63) == 0) sh2[t >> 6] = s2;
    __syncthreads();
    float var = (sh2[0] + sh2[1] + sh2[2] + sh2[3]) * (1.f / 512.f);
    float inv = rsqrtf(var + 1e-5f);
    float x1 = da * inv * lng[t] + lnb[t];
    float x2 = dc * inv * lng[t + 256] + lnb[t + 256];
    float g1 = 0.5f * x1 * (1.f + erff(x1 * 0.70710678118654752f));
    float g2 = 0.5f * x2 * (1.f + erff(x2 * 0.70710678118654752f));
    out[(long)row * 512 + t] = f2bf(g1);
    out[(long)row * 512 + t + 256] = f2bf(g2);
}

// ---------------- z = d @ Wz + bz -> log_sigmoid(+-z) ----------------
__global__ void k_z(const ushort_t* __restrict__ dmat, const float* __restrict__ Wz,
                    const float* __restrict__ bzp, float* __restrict__ lszp,
                    float* __restrict__ lszn) {
    int row = blockIdx.x * 4 + (threadIdx.x >> 6);
    int l = threadIdx.x & 63;
    const ushort_t* p = dmat + (long)row * 256 + l * 4;
    float4 w = *(const float4*)(Wz + l * 4);
    float s = bf2f(p[0]) * w.x + bf2f(p[1]) * w.y + bf2f(p[2]) * w.z + bf2f(p[3]) * w.w;
    s = wredsum(s);
    if (l == 0) {
        float z = s + bzp[0];
        lszp[row] = logsig(z);
        lszn[row] = logsig(-z);
    }
}

// ---------------- column argmax partial (over m-chunk) of inner ----------------
__global__ void k_colmaxA(const float* __restrict__ scores, const float* __restrict__ rowLSE,
                          const float* __restrict__ lsz0p, float* __restrict__ pcv,
                          int* __restrict__ pci) {
    int b = blockIdx.z;
    int n = blockIdx.x * 256 + threadIdx.x;
    int mstart = blockIdx.y * 256;
    const float* p = scores + (long)b * 4198401 + n;
    float bv = -3.4e38f;
    int bi = 0;
    for (int mm = 0; mm < 256; ++mm) {
        int m = mstart + mm;
        float v = 2.f * p[(long)m * 2049] - rowLSE[b * 2048 + m] + lsz0p[b * 2048 + m];
        if (v > bv) { bv = v; bi = m; }
    }
    int idx = (b * 8 + blockIdx.y) * 2048 + n;
    pcv[idx] = bv; pci[idx] = bi;
}

// ---------------- in-place sim -> inner, row max/argmax, border column ----------------
__global__ void k_scores(float* __restrict__ scores, const float* __restrict__ rowLSE,
                         const float* __restrict__ colLSE, const float* __restrict__ lsz0p,
                         const float* __restrict__ lsz1p, const float* __restrict__ lsz0n,
                         float* __restrict__ rmax, int* __restrict__ ridx) {
    int blk = blockIdx.x;
    int b = blk >> 11, m = blk & 2047;
    float* p = scores + (long)b * 4198401 + (long)m * 2049;
    int t = threadIdx.x;
    float rl = rowLSE[blk], l0 = lsz0p[blk];
    const float* cl = colLSE + b * 2048;
    const float* l1 = lsz1p + b * 2048;
    float bv = -3.4e38f;
    int bi = 0;
#pragma unroll
    for (int i = 0; i < 8; ++i) {
        int n = i * 256 + t;
        float v = 2.f * p[n] - rl - cl[n] + l0 + l1[n];
        p[n] = v;
        if (v > bv) { bv = v; bi = n; }
    }
    for (int o = 32; o; o >>= 1) {
        float ov = __shfl_xor(bv, o, 64);
        int oi = __shfl_xor(bi, o, 64);
        if (ov > bv || (ov == bv && oi < bi)) { bv = ov; bi = oi; }
    }
    __shared__ float sv[4];
    __shared__ int si[4];
    if ((t & 63) == 0) { sv[t >> 6] = bv; si[t >> 6] = bi; }
    __syncthreads();
    if (t == 0) {
        for (int w = 1; w < 4; ++w)
            if (sv[w] > bv || (sv[w] == bv && si[w] < bi)) { bv = sv[w]; bi = si[w]; }
        rmax[blk] = bv;
        ridx[blk] = bi;
        p[2048] = lsz0n[blk];
    }
}

// ---------------- combine col argmax, write border row + corner ----------------
__global__ void k_colmaxB(const float* __restrict__ pcv, const int* __restrict__ pci,
                          const float* __restrict__ lsz1n, float* __restrict__ scores,
                          int* __restrict__ cidx) {
    int idx = blockIdx.x * 256 + threadIdx.x;  // 8192
    int b = idx >> 11, n = idx & 2047;
    float bv = -3.4e38f;
    int bi = 0;
#pragma unroll
    for (int c = 0; c < 8; ++c) {
        float v = pcv[(b * 8 + c) * 2048 + n];
        int i = pci[(b * 8 + c) * 2048 + n];
        if (v > bv || (v == bv && i < bi)) { bv = v; bi = i; }
    }
    cidx[idx] = bi;
    scores[(long)b * 4198401 + 2048L * 2049 + n] = lsz1n[idx];
    if (n == 0) scores[(long)b * 4198401 + 2048L * 2049 + 2048] = 0.f;
}

__global__ void k_match0(const int* __restrict__ ridx, const int* __restrict__ cidx,
                         const float* __restrict__ rmax, float* __restrict__ m0out,
                         float* __restrict__ ms0out, float* __restrict__ ms0ws,
                         int* __restrict__ v0ws) {
    int idx = blockIdx.x * 256 + threadIdx.x;
    int b = idx >> 11, m = idx & 2047;
    int j = ridx[idx];
    bool mutual = (cidx[b * 2048 + j] == m);
    float e = mutual ? expf(rmax[idx]) : 0.f;
    bool valid = mutual && (e > 0.1f);
    m0out[idx] = valid ? (float)j : -1.f;
    ms0out[idx] = e;
    ms0ws[idx] = e;
    v0ws[idx] = valid ? 1 : 0;
}

__global__ void k_match1(const int* __restrict__ cidx, const int* __restrict__ ridx,
                         const float* __restrict__ ms0ws, const int* __restrict__ v0ws,
                         float* __restrict__ m1out, float* __restrict__ ms1out) {
    int idx = blockIdx.x * 256 + threadIdx.x;
    int b = idx >> 11, n = idx & 2047;
    int j = cidx[idx];
    bool mutual = (ridx[b * 2048 + j] == n);
    float ms1 = mutual ? ms0ws[b * 2048 + j] : 0.f;
    bool valid = mutual && (v0ws[b * 2048 + j] != 0);
    m1out[idx] = valid ? (float)j : -1.f;
    ms1out[idx] = ms1;
}

extern "C" void kernel_launch(void* const* d_in, const int* in_sizes, int n_in,
                              void* d_out, int out_size, void* d_ws, size_t ws_size,
                              hipStream_t stream) {
    (void)in_sizes; (void)n_in; (void)out_size; (void)ws_size;
    const float* x0  = (const float*)d_in[0];
    const float* x1  = (const float*)d_in[1];
    const float* adj = (const float*)d_in[2];
    const float* Wv  = (const float*)d_in[3];
    const float* bv  = (const float*)d_in[4];
    const float* Wo  = (const float*)d_in[5];
    const float* bo  = (const float*)d_in[6];
    const float* Wf1 = (const float*)d_in[7];
    const float* bf1 = (const float*)d_in[8];
    const float* lng = (const float*)d_in[9];
    const float* lnb = (const float*)d_in[10];
    const float* Wf2 = (const float*)d_in[11];
    const float* bf2 = (const float*)d_in[12];
    const float* Wfp = (const float*)d_in[13];
    const float* bfp = (const float*)d_in[14];
    const float* Wz  = (const float*)d_in[15];
    const float* bz  = (const float*)d_in[16];

    float* out = (float*)d_out;
    float* scores  = out;
    float* out_m0  = out + 16793604;
    float* out_m1  = out_m0 + 8192;
    float* out_ms0 = out_m1 + 8192;
    float* out_ms1 = out_ms0 + 8192;

    char* base = (char*)d_ws;
    // Big overlay region: A01+At10 (phase 1) then h/g/d/md (phase 2) — exactly 64 MiB
    char* Rbig = base;
    ushort_t* A01  = (ushort_t*)Rbig;
    ushort_t* At10 = (ushort_t*)(Rbig + 33554432);
    float*    h0   = (float*)Rbig;
    float*    h1   = (float*)(Rbig + 16777216);
    ushort_t* g0   = (ushort_t*)(Rbig + 33554432);
    ushort_t* g1   = (ushort_t*)(Rbig + 41943040);
    ushort_t* d0b  = (ushort_t*)(Rbig + 50331648);
    ushort_t* d1b  = (ushort_t*)(Rbig + 54525952);
    ushort_t* md0  = (ushort_t*)(Rbig + 58720256);
    ushort_t* md1  = (ushort_t*)(Rbig + 62914560);
    size_t off = 67108864;
    auto alloc = [&](size_t sz) { char* p = base + off; off += (sz + 255) & ~(size_t)255; return p; };
    ushort_t* cat0 = (ushort_t*)alloc(8388608);
    ushort_t* cat1 = (ushort_t*)alloc(8388608);
    ushort_t* u0   = (ushort_t*)alloc(4194304);
    ushort_t* u1   = (ushort_t*)alloc(4194304);
    ushort_t* u0t  = (ushort_t*)alloc(4194304);
    ushort_t* u1t  = (ushort_t*)alloc(4194304);
    ushort_t* Wovb = (ushort_t*)alloc(131072);
    ushort_t* Wf1b = (ushort_t*)alloc(524288);
    ushort_t* Wf2b = (ushort_t*)alloc(262144);
    ushort_t* Wfpb = (ushort_t*)alloc(131072);
    float* bvo     = (float*)alloc(1024);
    float* rlse    = (float*)alloc(32768);
    float* clse    = (float*)alloc(32768);
    float* pm      = (float*)alloc(262144);
    float* ps      = (float*)alloc(262144);
    float* rowLSE  = (float*)alloc(32768);
    float* colLSE  = (float*)alloc(32768);
    float* pcv     = (float*)alloc(262144);
    int*   pci     = (int*)alloc(262144);
    float* rmax    = (float*)alloc(32768);
    int*   ridx    = (int*)alloc(32768);
    int*   cidx    = (int*)alloc(32768);
    float* lsz0p   = (float*)alloc(32768);
    float* lsz0n   = (float*)alloc(32768);
    float* lsz1p   = (float*)alloc(32768);
    float* lsz1n   = (float*)alloc(32768);
    float* ms0ws   = (float*)alloc(32768);
    int*   v0ws    = (int*)alloc(32768);

    // ---- weight prep + casts ----
    k_wov<<<256, 256, 0, stream>>>(Wo, Wv, bv, bo, Wovb, bvo);
    k_cast_flat<<<1024, 256, 0, stream>>>(Wf1, Wf1b, 262144);
    k_cast_flat<<<512, 256, 0, stream>>>(Wf2, Wf2b, 131072);
    k_cast_flat<<<256, 256, 0, stream>>>(Wfp, Wfpb, 65536);
    k_cast_x<<<8192, 256, 0, stream>>>(x0, cat0);
    k_cast_x<<<8192, 256, 0, stream>>>(x1, cat1);

    // ---- adjacency softmax stats + materialize ----
    k_rowlse<<<8192, 256, 0, stream>>>(adj, 2048, 4194304L, rlse);
    k_colpart<<<dim3(8, 8, 4), 256, 0, stream>>>(adj, 2048, 4194304L, pm, ps);
    k_colcomb<<<32, 256, 0, stream>>>(pm, ps, clse);
    k_mat<<<dim3(32, 32, 4), 256, 0, stream>>>(adj, rlse, clse, A01, At10);

    // ---- u = x @ Wov.T + bvo  (then transpose) ----
    gemm_bt<<<dim3(64, 2, 1), 256, 0, stream>>>(cat0, 0L, 512, Wovb, 0L, 256, 256, EpiB16{u0, bvo});
    gemm_bt<<<dim3(64, 2, 1), 256, 0, stream>>>(cat1, 0L, 512, Wovb, 0L, 256, 256, EpiB16{u1, bvo});
    k_tr<<<dim3(4, 32, 4), 256, 0, stream>>>(u0, u0t);
    k_tr<<<dim3(4, 32, 4), 256, 0, stream>>>(u1, u1t);

    // ---- m0 = A01 @ u1, m1 = At10 @ u0 (into cat[...,256:512]) ----
    gemm_bt<<<dim3(16, 2, 4), 256, 0, stream>>>(A01, 4194304L, 2048, u1t, 524288L, 2048, 2048, EpiCat{cat0});
    gemm_bt<<<dim3(16, 2, 4), 256, 0, stream>>>(At10, 4194304L, 2048, u0t, 524288L, 2048, 2048, EpiCat{cat1});

    // ---- h = cat @ Wf1.T + bf1 ----
    gemm_bt<<<dim3(64, 4, 1), 256, 0, stream>>>(cat0, 0L, 512, Wf1b, 0L, 512, 512, EpiH{h0, bf1});
    gemm_bt<<<dim3(64, 4, 1), 256, 0, stream>>>(cat1, 0L, 512, Wf1b, 0L, 512, 512, EpiH{h1, bf1});
    k_ln<<<8192, 256, 0, stream>>>(h0, lng, lnb, g0);
    k_ln<<<8192, 256, 0, stream>>>(h1, lng, lnb, g1);

    // ---- d = x + g @ Wf2.T + bf2 ----
    gemm_bt<<<dim3(64, 2, 1), 256, 0, stream>>>(g0, 0L, 512, Wf2b, 0L, 512, 512, EpiD{d0b, bf2, x0});
    gemm_bt<<<dim3(64, 2, 1), 256, 0, stream>>>(g1, 0L, 512, Wf2b, 0L, 512, 512, EpiD{d1b, bf2, x1});

    // ---- z / log_sigmoid ----
    k_z<<<2048, 256, 0, stream>>>(d0b, Wz, bz, lsz0p, lsz0n);
    k_z<<<2048, 256, 0, stream>>>(d1b, Wz, bz, lsz1p, lsz1n);

    // ---- md = (d @ Wfp.T + bfp)/4 ----
    gemm_bt<<<dim3(64, 2, 1), 256, 0, stream>>>(d0b, 0L, 256, Wfpb, 0L, 256, 256, EpiMd{md0, bfp});
    gemm_bt<<<dim3(64, 2, 1), 256, 0, stream>>>(d1b, 0L, 256, Wfpb, 0L, 256, 256, EpiMd{md1, bfp});

    // ---- sim = md0 @ md1^T -> scores area (ld 2049) ----
    gemm_bt<<<dim3(16, 16, 4), 256, 0, stream>>>(md0, 524288L, 256, md1, 524288L, 256, 256, EpiSim{scores});

    // ---- log-softmax stats over sim ----
    k_rowlse<<<8192, 256, 0, stream>>>(scores, 2049, 4198401L, rowLSE);
    k_colpart<<<dim3(8, 8, 4), 256, 0, stream>>>(scores, 2049, 4198401L, pm, ps);
    k_colcomb<<<32, 256, 0, stream>>>(pm, ps, colLSE);

    // ---- col argmax partials (reads sim BEFORE in-place transform) ----
    k_colmaxA<<<dim3(8, 8, 4), 256, 0, stream>>>(scores, rowLSE, lsz0p, pcv, pci);
    // ---- in-place inner + row argmax + border col ----
    k_scores<<<8192, 256, 0, stream>>>(scores, rowLSE, colLSE, lsz0p, lsz1p, lsz0n, rmax, ridx);
    // ---- combine col argmax + border row + corner ----
    k_colmaxB<<<32, 256, 0, stream>>>(pcv, pci, lsz1n, scores, cidx);

    // ---- mutual matching ----
    k_match0<<<32, 256, 0, stream>>>(ridx, cidx, rmax, out_m0, out_ms0, ms0ws, v0ws);
    k_match1<<<32, 256, 0, stream>>>(cidx, ridx, ms0ws, v0ws, out_m1, out_ms1);
}

// Round 2
// 684.590 us; speedup vs baseline: 1.5068x; 1.5068x over previous
//
#include <hip/hip_runtime.h>

typedef unsigned short ushort_t;
typedef __bf16 bf16x8 __attribute__((ext_vector_type(8)));
typedef float f32x4 __attribute__((ext_vector_type(4)));

__device__ __forceinline__ ushort_t f2bf(float f) {
    unsigned int u = __float_as_uint(f);
    unsigned int r = (u + 0x7fffu + ((u >> 16) & 1u)) >> 16;
    return (ushort_t)r;
}
__device__ __forceinline__ float bf2f(ushort_t u) {
    return __uint_as_float(((unsigned int)u) << 16);
}
__device__ __forceinline__ uint2 pack4(float a, float b, float c, float d) {
    uint2 o;
    o.x = (unsigned)f2bf(a) | ((unsigned)f2bf(b) << 16);
    o.y = (unsigned)f2bf(c) | ((unsigned)f2bf(d) << 16);
    return o;
}
__device__ __forceinline__ float wredsum(float v) {
    for (int o = 32; o; o >>= 1) v += __shfl_xor(v, o, 64);
    return v;
}
__device__ __forceinline__ float wredmax(float v) {
    for (int o = 32; o; o >>= 1) v = fmaxf(v, __shfl_xor(v, o, 64));
    return v;
}
__device__ __forceinline__ float logsig(float z) {
    return (z >= 0.f) ? -log1pf(expf(-z)) : (z - log1pf(expf(z)));
}

// ---------------- weight prep: Wov = Wo @ Wv, bvo = Wo@bv + bo ----------------
__global__ void k_wov(const float* __restrict__ Wo, const float* __restrict__ Wv,
                      const float* __restrict__ bvv, const float* __restrict__ bo,
                      ushort_t* __restrict__ Wovb, float* __restrict__ bvo) {
    int o = blockIdx.x, k = threadIdx.x;
    float s = 0.f;
    for (int j = 0; j < 256; ++j) s += Wo[o * 256 + j] * Wv[j * 256 + k];
    Wovb[o * 256 + k] = f2bf(s);
    float pb = Wo[o * 256 + k] * bvv[k];
    pb = wredsum(pb);
    __shared__ float sh[4];
    if ((k & 63) == 0) sh[k >> 6] = pb;
    __syncthreads();
    if (k == 0) bvo[o] = sh[0] + sh[1] + sh[2] + sh[3] + bo[o];
}

__global__ void k_cast_flat(const float* __restrict__ src, ushort_t* __restrict__ dst, int n) {
    int i = blockIdx.x * 256 + threadIdx.x;
    if (i < n) dst[i] = f2bf(src[i]);
}

// x (R,256) fp32 -> cat (R,512) bf16 at cols [0,256)
__global__ void k_cast_x(const float* __restrict__ src, ushort_t* __restrict__ dst) {
    long i = (long)blockIdx.x * 256 + threadIdx.x;
    long r = i >> 8;
    int c = (int)(i & 255);
    dst[r * 512 + c] = f2bf(src[i]);
}

// ---------------- row LSE (axis=-1) over 2048-wide rows ----------------
__global__ void k_rowlse(const float* __restrict__ src, int ld, long bstride,
                         float* __restrict__ out) {
    int blk = blockIdx.x;
    int b = blk >> 11, m = blk & 2047;
    const float* p = src + (long)b * bstride + (long)m * ld;
    int t = threadIdx.x;
    float v[8];
    float mx = -3.4e38f;
#pragma unroll
    for (int i = 0; i < 8; ++i) { v[i] = p[i * 256 + t]; mx = fmaxf(mx, v[i]); }
    mx = wredmax(mx);
    __shared__ float sh[4];
    if ((t & 63) == 0) sh[t >> 6] = mx;
    __syncthreads();
    mx = fmaxf(fmaxf(sh[0], sh[1]), fmaxf(sh[2], sh[3]));
    float s = 0.f;
#pragma unroll
    for (int i = 0; i < 8; ++i) s += expf(v[i] - mx);
    s = wredsum(s);
    __shared__ float sh2[4];
    if ((t & 63) == 0) sh2[t >> 6] = s;
    __syncthreads();
    if (t == 0) out[blk] = mx + logf(sh2[0] + sh2[1] + sh2[2] + sh2[3]);
}

// ---------------- column LSE partials, 128-row chunks (16 chunks) ----------------
__global__ void k_colpart(const float* __restrict__ src, int ld, long bstride,
                          float* __restrict__ pm, float* __restrict__ ps) {
    int b = blockIdx.z;
    int n = blockIdx.x * 256 + threadIdx.x;
    int mstart = blockIdx.y * 128;
    const float* p = src + (long)b * bstride + n;
    float mx = -3.4e38f, s = 0.f;
    for (int mm = 0; mm < 128; ++mm) {
        float v = p[(long)(mstart + mm) * ld];
        if (v > mx) { s = s * expf(mx - v) + 1.f; mx = v; }
        else s += expf(v - mx);
    }
    int idx = (b * 16 + blockIdx.y) * 2048 + n;
    pm[idx] = mx; ps[idx] = s;
}

__global__ void k_colcomb(const float* __restrict__ pm, const float* __restrict__ ps,
                          float* __restrict__ out) {
    int idx = blockIdx.x * 256 + threadIdx.x;  // 8192
    int b = idx >> 11, n = idx & 2047;
    float mx = -3.4e38f;
#pragma unroll
    for (int c = 0; c < 16; ++c) mx = fmaxf(mx, pm[(b * 16 + c) * 2048 + n]);
    float s = 0.f;
#pragma unroll
    for (int c = 0; c < 16; ++c) s += ps[(b * 16 + c) * 2048 + n] * expf(pm[(b * 16 + c) * 2048 + n] - mx);
    out[idx] = mx + logf(s);
}

// ---------------- fused column LSE partial + column argmax of transformed inner ----------------
__global__ void k_colstat(const float* __restrict__ scores, const float* __restrict__ rowLSE,
                          const float* __restrict__ lszp, float* __restrict__ pm,
                          float* __restrict__ ps, float* __restrict__ pcv,
                          int* __restrict__ pci) {
    int b = blockIdx.z;
    int n = blockIdx.x * 256 + threadIdx.x;
    int mstart = blockIdx.y * 128;
    const float* p = scores + (long)b * 4198401 + n;
    float mx = -3.4e38f, s = 0.f;
    float bv = -3.4e38f;
    int bi = 0;
    for (int mm = 0; mm < 128; ++mm) {
        int m = mstart + mm;
        float v = p[(long)m * 2049];
        if (v > mx) { s = s * expf(mx - v) + 1.f; mx = v; }
        else s += expf(v - mx);
        float tv = 2.f * v - rowLSE[b * 2048 + m] + lszp[b * 2048 + m];
        if (tv > bv) { bv = tv; bi = m; }
    }
    int idx = (b * 16 + blockIdx.y) * 2048 + n;
    pm[idx] = mx; ps[idx] = s;
    pcv[idx] = bv; pci[idx] = bi;
}

// ---------------- materialize A01 (B,M,N) bf16 and At10 (B,N,M) bf16 ----------------
__global__ void k_mat(const float* __restrict__ adj, const float* __restrict__ rlse,
                      const float* __restrict__ clse, ushort_t* __restrict__ A01,
                      ushort_t* __restrict__ At10) {
    int b = blockIdx.z;
    int n0 = blockIdx.x * 64, m0 = blockIdx.y * 64;
    __shared__ ushort_t T[64][72];
    int t = threadIdx.x;
    int r = t >> 4, cq = t & 15;
    const float* base = adj + ((long)b * 2048 + m0) * 2048 + n0;
#pragma unroll
    for (int p = 0; p < 4; ++p) {
        int row = p * 16 + r;
        float4 v = *(const float4*)(base + (long)row * 2048 + cq * 4);
        float vf[4] = {v.x, v.y, v.z, v.w};
        float rl = rlse[b * 2048 + m0 + row];
        ushort_t e[4];
#pragma unroll
        for (int j = 0; j < 4; ++j) e[j] = f2bf(expf(vf[j] - rl));
        uint2 o;
        o.x = (unsigned)e[0] | ((unsigned)e[1] << 16);
        o.y = (unsigned)e[2] | ((unsigned)e[3] << 16);
        *(uint2*)&A01[((long)b * 2048 + m0 + row) * 2048 + n0 + cq * 4] = o;
#pragma unroll
        for (int j = 0; j < 4; ++j) {
            float cl = clse[b * 2048 + n0 + cq * 4 + j];
            T[cq * 4 + j][row] = f2bf(expf(vf[j] - cl));
        }
    }
    __syncthreads();
#pragma unroll
    for (int p = 0; p < 4; ++p) {
        int rn = p * 16 + r;
        uint2 o;
        o.x = (unsigned)T[rn][cq * 4 + 0] | ((unsigned)T[rn][cq * 4 + 1] << 16);
        o.y = (unsigned)T[rn][cq * 4 + 2] | ((unsigned)T[rn][cq * 4 + 3] << 16);
        *(uint2*)&At10[((long)b * 2048 + n0 + rn) * 2048 + m0 + cq * 4] = o;
    }
}

// ---------------- bf16 transpose of 8 slabs (2048,256)->(256,2048); dst slab = src^4 ----------------
__global__ void k_tr(const ushort_t* __restrict__ src, ushort_t* __restrict__ dst) {
    int z = blockIdx.z;
    int c0 = blockIdx.x * 64, r0 = blockIdx.y * 64;
    const ushort_t* s = src + (long)z * 524288;
    ushort_t* d = dst + (long)(z ^ 4) * 524288;
    __shared__ ushort_t T[64][68];
    int t = threadIdx.x;
    int ir = t >> 4, jc = t & 15;
#pragma unroll
    for (int p = 0; p < 4; ++p) {
        int row = p * 16 + ir;
        uint2 v = *(const uint2*)&s[(long)(r0 + row) * 256 + c0 + jc * 4];
        T[jc * 4 + 0][row] = (ushort_t)(v.x & 0xffff);
        T[jc * 4 + 1][row] = (ushort_t)(v.x >> 16);
        T[jc * 4 + 2][row] = (ushort_t)(v.y & 0xffff);
        T[jc * 4 + 3][row] = (ushort_t)(v.y >> 16);
    }
    __syncthreads();
#pragma unroll
    for (int p = 0; p < 4; ++p) {
        int crow = p * 16 + ir;
        uint2 o;
        o.x = (unsigned)T[crow][jc * 4 + 0] | ((unsigned)T[crow][jc * 4 + 1] << 16);
        o.y = (unsigned)T[crow][jc * 4 + 2] | ((unsigned)T[crow][jc * 4 + 3] << 16);
        *(uint2*)&d[(long)(c0 + crow) * 2048 + r0 + jc * 4] = o;
    }
}

// ---------------- MFMA GEMM: C[b,r,c] = sum_k A[b,r,k] * Bt[b,c,k] ----------------
// 128x128 tile, BK=64, 4 waves of 64x64, 16x16x32 bf16 MFMA.
// blockIdx.y encodes (n_tile, k_slice): nt = by % ntn, slice = by / ntn.
// Each slice handles K-range [slice*Kslice, (slice+1)*Kslice).
template <class Epi>
__global__ __launch_bounds__(256, 2) void gemm_bt(const ushort_t* __restrict__ A, long sA, int lda,
                                                  const ushort_t* __restrict__ Bt, long sB, int ldb,
                                                  int Kslice, int ntn, Epi epi) {
    __shared__ ushort_t lA[8 * 130 * 8];
    __shared__ ushort_t lB[8 * 130 * 8];
    const int b = blockIdx.z;
    const int nt = blockIdx.y % ntn, slice = blockIdx.y / ntn;
    const int m0 = blockIdx.x * 128, n0 = nt * 128;
    const int kbase = slice * Kslice;
    const ushort_t* Ab = A + (long)b * sA;
    const ushort_t* Bb = Bt + (long)b * sB;
    const int t = threadIdx.x;
    const int lane = t & 63, wave = t >> 6;
    const int wm = (wave & 1) * 64, wn = (wave >> 1) * 64;
    const int q = lane >> 4, lm = lane & 15;

    const int4* pa[4];
    const int4* pb[4];
    int arow[4], akc[4];
#pragma unroll
    for (int i = 0; i < 4; ++i) {
        int c = i * 256 + t;
        arow[i] = c >> 3;
        akc[i] = c & 7;
        pa[i] = (const int4*)(Ab + (long)(m0 + arow[i]) * lda + kbase + akc[i] * 8);
        pb[i] = (const int4*)(Bb + (long)(n0 + arow[i]) * ldb + kbase + akc[i] * 8);
    }
    f32x4 zero = {0.f, 0.f, 0.f, 0.f};
    f32x4 acc[4][4];
#pragma unroll
    for (int mi = 0; mi < 4; ++mi)
#pragma unroll
        for (int ni = 0; ni < 4; ++ni) acc[mi][ni] = zero;

    int4 ra[4], rb[4];
#pragma unroll
    for (int i = 0; i < 4; ++i) { ra[i] = pa[i][0]; rb[i] = pb[i][0]; }

    const int nkt = Kslice >> 6;
    for (int kt = 0; kt < nkt; ++kt) {
        __syncthreads();
#pragma unroll
        for (int i = 0; i < 4; ++i) {
            *(int4*)&lA[(akc[i] * 130 + arow[i]) * 8] = ra[i];
            *(int4*)&lB[(akc[i] * 130 + arow[i]) * 8] = rb[i];
        }
        __syncthreads();
        if (kt + 1 < nkt) {
#pragma unroll
            for (int i = 0; i < 4; ++i) { ra[i] = pa[i][(kt + 1) * 8]; rb[i] = pb[i][(kt + 1) * 8]; }
        }
#pragma unroll
        for (int kk = 0; kk < 2; ++kk) {
            bf16x8 af[4], bfr[4];
#pragma unroll
            for (int mi = 0; mi < 4; ++mi)
                af[mi] = *(const bf16x8*)&lA[((kk * 4 + q) * 130 + wm + mi * 16 + lm) * 8];
#pragma unroll
            for (int ni = 0; ni < 4; ++ni)
                bfr[ni] = *(const bf16x8*)&lB[((kk * 4 + q) * 130 + wn + ni * 16 + lm) * 8];
#pragma unroll
            for (int mi = 0; mi < 4; ++mi)
#pragma unroll
                for (int ni = 0; ni < 4; ++ni)
                    acc[mi][ni] = __builtin_amdgcn_mfma_f32_16x16x32_bf16(af[mi], bfr[ni], acc[mi][ni], 0, 0, 0);
        }
    }
#pragma unroll
    for (int mi = 0; mi < 4; ++mi)
#pragma unroll
        for (int ni = 0; ni < 4; ++ni)
#pragma unroll
            for (int r2 = 0; r2 < 4; ++r2) {
                int row = m0 + wm + mi * 16 + q * 4 + r2;
                int col = n0 + wn + ni * 16 + lm;
                epi(b, slice, row, col, acc[mi][ni][r2]);
            }
}

// Epilogues
struct EpiOut {  // bf16 = (v + bias[c]) * scale, ld 256
    ushort_t* dst; const float* bias; float scale;
    __device__ void operator()(int b, int s, int r, int c, float v) const {
        dst[(long)r * 256 + c] = f2bf((v + bias[c]) * scale);
    }
};
struct EpiCat {  // direct bf16 into cat[b*2048+r][256+c] (fallback, no split)
    ushort_t* dst;
    __device__ void operator()(int b, int s, int r, int c, float v) const {
        dst[((long)b * 2048 + r) * 512 + 256 + c] = f2bf(v);
    }
};
struct EpiPart {  // fp32 partial: dst[s*sstride + b*bstride + r*256 + c]
    float* dst; long bstride; long sstride;
    __device__ void operator()(int b, int s, int r, int c, float v) const {
        dst[(long)s * sstride + (long)b * bstride + (long)r * 256 + c] = v;
    }
};
struct EpiH {  // fp32 + bias, ld 512
    float* dst; const float* bias;
    __device__ void operator()(int b, int s, int r, int c, float v) const {
        dst[(long)r * 512 + c] = v + bias[c];
    }
};
struct EpiD {  // direct bf16 = v + bias + resid (fallback, no split)
    ushort_t* dst; const float* bias; const float* x0; const float* x1;
    __device__ void operator()(int b, int s, int r, int c, float v) const {
        float rx = (r < 8192) ? x0[(long)r * 256 + c] : x1[(long)(r - 8192) * 256 + c];
        dst[(long)r * 256 + c] = f2bf(v + bias[c] + rx);
    }
};
struct EpiSim {  // fp32 into scores area, ld 2049
    float* dst;
    __device__ void operator()(int b, int s, int r, int c, float v) const {
        dst[(long)b * 4198401 + (long)r * 2049 + c] = v;
    }
};

// ---------------- split-K combines ----------------
__global__ void k_comb_m(const float* __restrict__ mp, int ks, ushort_t* __restrict__ cat) {
    long e = ((long)blockIdx.x * 256 + threadIdx.x) * 4;  // total 8*2048*256
    float4 s = *(const float4*)(mp + e);
    for (int sl = 1; sl < ks; ++sl) {
        float4 tv = *(const float4*)(mp + (long)sl * 4194304 + e);
        s.x += tv.x; s.y += tv.y; s.z += tv.z; s.w += tv.w;
    }
    long row = e >> 8;
    int c = (int)(e & 255);
    uint2 o = pack4(s.x, s.y, s.z, s.w);
    *(uint2*)&cat[row * 512 + 256 + c] = o;
}

__global__ void k_comb_d(const float* __restrict__ dp, int ks, const float* __restrict__ bias,
                         const float* __restrict__ x0, const float* __restrict__ x1,
                         ushort_t* __restrict__ d) {
    long e = ((long)blockIdx.x * 256 + threadIdx.x) * 4;  // total 16384*256
    float4 s = *(const float4*)(dp + e);
    for (int sl = 1; sl < ks; ++sl) {
        float4 tv = *(const float4*)(dp + (long)sl * 4194304 + e);
        s.x += tv.x; s.y += tv.y; s.z += tv.z; s.w += tv.w;
    }
    long row = e >> 8;
    int c = (int)(e & 255);
    float4 bi = *(const float4*)(bias + c);
    float4 rx = (row < 8192) ? *(const float4*)(x0 + e) : *(const float4*)(x1 + e - 2097152);
    uint2 o = pack4(s.x + bi.x + rx.x, s.y + bi.y + rx.y, s.z + bi.z + rx.z, s.w + bi.w + rx.w);
    *(uint2*)&d[e] = o;
}

// ---------------- LN + GELU (rows of 512) ----------------
__global__ void k_ln(const float* __restrict__ h, const float* __restrict__ lng,
                     const float* __restrict__ lnb, ushort_t* __restrict__ out) {
    int row = blockIdx.x;
    int t = threadIdx.x;
    const float* p = h + (long)row * 512;
    float a = p[t], c = p[t + 256];
    float s = wredsum(a + c);
    __shared__ float sh[4];
    if ((t & 63) == 0) sh[t >> 6] = s;
    __syncthreads();
    float mean = (sh[0] + sh[1] + sh[2] + sh[3]) * (1.f / 512.f);
    float da = a - mean, dc = c - mean;
    float s2 = wredsum(da * da + dc * dc);
    __shared__ float sh2[4];
    if ((t & 63) == 0) sh2[t >> 6] = s2;
    __syncthreads();
    float var = (sh2[0] + sh2[1] + sh2[2] + sh2[3]) * (1.f / 512.f);
    float inv = rsqrtf(var + 1e-5f);
    float x1 = da * inv * lng[t] + lnb[t];
    float x2 = dc * inv * lng[t + 256] + lnb[t + 256];
    float g1 = 0.5f * x1 * (1.f + erff(x1 * 0.70710678118654752f));
    float g2 = 0.5f * x2 * (1.f + erff(x2 * 0.70710678118654752f));
    out[(long)row * 512 + t] = f2bf(g1);
    out[(long)row * 512 + t + 256] = f2bf(g2);
}

// ---------------- z = d @ Wz + bz -> log_sigmoid(+-z); 16384 merged rows ----------------
__global__ void k_z(const ushort_t* __restrict__ dmat, const float* __restrict__ Wz,
                    const float* __restrict__ bzp, float* __restrict__ lszp,
                    float* __restrict__ lszn) {
    int row = blockIdx.x * 4 + (threadIdx.x >> 6);
    int l = threadIdx.x & 63;
    const ushort_t* p = dmat + (long)row * 256 + l * 4;
    float4 w = *(const float4*)(Wz + l * 4);
    float s = bf2f(p[0]) * w.x + bf2f(p[1]) * w.y + bf2f(p[2]) * w.z + bf2f(p[3]) * w.w;
    s = wredsum(s);
    if (l == 0) {
        float z = s + bzp[0];
        lszp[row] = logsig(z);
        lszn[row] = logsig(-z);
    }
}

// ---------------- in-place sim -> inner, row max/argmax, border column ----------------
__global__ void k_scores(float* __restrict__ scores, const float* __restrict__ rowLSE,
                         const float* __restrict__ colLSE, const float* __restrict__ lszp,
                         const float* __restrict__ lszn, float* __restrict__ rmax,
                         int* __restrict__ ridx) {
    int blk = blockIdx.x;
    int b = blk >> 11;
    float* p = scores + (long)b * 4198401 + (long)(blk & 2047) * 2049;
    int t = threadIdx.x;
    float rl = rowLSE[blk], l0 = lszp[blk];
    const float* cl = colLSE + b * 2048;
    const float* l1 = lszp + 8192 + b * 2048;
    float bv = -3.4e38f;
    int bi = 0;
#pragma unroll
    for (int i = 0; i < 8; ++i) {
        int n = i * 256 + t;
        float v = 2.f * p[n] - rl - cl[n] + l0 + l1[n];
        p[n] = v;
        if (v > bv) { bv = v; bi = n; }
    }
    for (int o = 32; o; o >>= 1) {
        float ov = __shfl_xor(bv, o, 64);
        int oi = __shfl_xor(bi, o, 64);
        if (ov > bv || (ov == bv && oi < bi)) { bv = ov; bi = oi; }
    }
    __shared__ float sv[4];
    __shared__ int si[4];
    if ((t & 63) == 0) { sv[t >> 6] = bv; si[t >> 6] = bi; }
    __syncthreads();
    if (t == 0) {
        for (int w = 1; w < 4; ++w)
            if (sv[w] > bv || (sv[w] == bv && si[w] < bi)) { bv = sv[w]; bi = si[w]; }
        rmax[blk] = bv;
        ridx[blk] = bi;
        p[2048] = lszn[blk];
    }
}

// ---------------- combine col argmax chunks, write border row + corner ----------------
__global__ void k_colmaxB(const float* __restrict__ pcv, const int* __restrict__ pci,
                          const float* __restrict__ lszn, float* __restrict__ scores,
                          int* __restrict__ cidx) {
    int idx = blockIdx.x * 256 + threadIdx.x;  // 8192
    int b = idx >> 11, n = idx & 2047;
    float bv = -3.4e38f;
    int bi = 0;
#pragma unroll
    for (int c = 0; c < 16; ++c) {
        float v = pcv[(b * 16 + c) * 2048 + n];
        int i = pci[(b * 16 + c) * 2048 + n];
        if (v > bv || (v == bv && i < bi)) { bv = v; bi = i; }
    }
    cidx[idx] = bi;
    scores[(long)b * 4198401 + 2048L * 2049 + n] = lszn[8192 + idx];
    if (n == 0) scores[(long)b * 4198401 + 2048L * 2049 + 2048] = 0.f;
}

__global__ void k_match0(const int* __restrict__ ridx, const int* __restrict__ cidx,
                         const float* __restrict__ rmax, float* __restrict__ m0out,
                         float* __restrict__ ms0out, float* __restrict__ ms0ws,
                         int* __restrict__ v0ws) {
    int idx = blockIdx.x * 256 + threadIdx.x;
    int b = idx >> 11, m = idx & 2047;
    int j = ridx[idx];
    bool mutual = (cidx[b * 2048 + j] == m);
    float e = mutual ? expf(rmax[idx]) : 0.f;
    bool valid = mutual && (e > 0.1f);
    m0out[idx] = valid ? (float)j : -1.f;
    ms0out[idx] = e;
    ms0ws[idx] = e;
    v0ws[idx] = valid ? 1 : 0;
}

__global__ void k_match1(const int* __restrict__ cidx, const int* __restrict__ ridx,
                         const float* __restrict__ ms0ws, const int* __restrict__ v0ws,
                         float* __restrict__ m1out, float* __restrict__ ms1out) {
    int idx = blockIdx.x * 256 + threadIdx.x;
    int b = idx >> 11, n = idx & 2047;
    int j = cidx[idx];
    bool mutual = (ridx[b * 2048 + j] == n);
    float ms1 = mutual ? ms0ws[b * 2048 + j] : 0.f;
    bool valid = mutual && (v0ws[b * 2048 + j] != 0);
    m1out[idx] = valid ? (float)j : -1.f;
    ms1out[idx] = ms1;
}

extern "C" void kernel_launch(void* const* d_in, const int* in_sizes, int n_in,
                              void* d_out, int out_size, void* d_ws, size_t ws_size,
                              hipStream_t stream) {
    (void)in_sizes; (void)n_in; (void)out_size;
    const float* x0  = (const float*)d_in[0];
    const float* x1  = (const float*)d_in[1];
    const float* adj = (const float*)d_in[2];
    const float* Wv  = (const float*)d_in[3];
    const float* bv  = (const float*)d_in[4];
    const float* Wo  = (const float*)d_in[5];
    const float* bo  = (const float*)d_in[6];
    const float* Wf1 = (const float*)d_in[7];
    const float* bf1 = (const float*)d_in[8];
    const float* lng = (const float*)d_in[9];
    const float* lnb = (const float*)d_in[10];
    const float* Wf2 = (const float*)d_in[11];
    const float* bf2 = (const float*)d_in[12];
    const float* Wfp = (const float*)d_in[13];
    const float* bfp = (const float*)d_in[14];
    const float* Wz  = (const float*)d_in[15];
    const float* bz  = (const float*)d_in[16];

    float* out = (float*)d_out;
    float* scores  = out;
    float* out_m0  = out + 16793604;
    float* out_m1  = out_m0 + 8192;
    float* out_ms0 = out_m1 + 8192;
    float* out_ms1 = out_ms0 + 8192;

    char* base = (char*)d_ws;
    // Rbig overlay (64 MiB): phase1 = A01(32M)+At10(32M); phase2 = h(32M)+g(16M)+d(8M)+md(8M)
    char* Rbig = base;
    ushort_t* A01  = (ushort_t*)Rbig;                    // 8 slabs of 2048x2048 (A01 b0..3, At10 b0..3)
    float*    hbuf = (float*)Rbig;                       // 16384x512 fp32
    ushort_t* gbuf = (ushort_t*)(Rbig + 33554432);       // 16384x512 bf16
    ushort_t* dbuf = (ushort_t*)(Rbig + 50331648);       // 16384x256 bf16 (8 slabs of 2048x256)
    ushort_t* mdb  = (ushort_t*)(Rbig + 58720256);       // 16384x256 bf16 (8 slabs)
    size_t off = 67108864;
    auto alloc = [&](size_t sz) { char* p = base + off; off += (sz + 255) & ~(size_t)255; return p; };
    ushort_t* cat  = (ushort_t*)alloc(16777216);   // 16384x512 bf16
    ushort_t* ubuf = (ushort_t*)alloc(8388608);    // 16384x256 bf16
    ushort_t* ut   = (ushort_t*)alloc(8388608);    // 8 slabs 256x2048 bf16 (slab-swapped)
    ushort_t* Wovb = (ushort_t*)alloc(131072);
    ushort_t* Wf1b = (ushort_t*)alloc(524288);
    ushort_t* Wf2b = (ushort_t*)alloc(262144);
    ushort_t* Wfpb = (ushort_t*)alloc(131072);
    float* bvo     = (float*)alloc(1024);
    float* rlse    = (float*)alloc(32768);
    float* clse    = (float*)alloc(32768);
    float* pm      = (float*)alloc(524288);
    float* ps      = (float*)alloc(524288);
    float* rowLSE  = (float*)alloc(32768);
    float* colLSE  = (float*)alloc(32768);
    float* pcv     = (float*)alloc(524288);
    int*   pci     = (int*)alloc(524288);
    float* rmax    = (float*)alloc(32768);
    int*   ridx    = (int*)alloc(32768);
    int*   cidx    = (int*)alloc(32768);
    float* lszp    = (float*)alloc(65536);
    float* lszn    = (float*)alloc(65536);
    float* ms0ws   = (float*)alloc(32768);
    int*   v0ws    = (int*)alloc(32768);
    // split-K partial buffer takes whatever remains
    float* part = (float*)(base + off);
    size_t avail = (ws_size > off) ? (ws_size - off) : 0;
    int ks_m = 1, ks_d = 1;
    if (avail >= (size_t)4 * 16777216) { ks_m = 4; ks_d = 2; }
    else if (avail >= (size_t)2 * 16777216) { ks_m = 2; ks_d = 2; }

    // ---- weight prep + casts ----
    k_wov<<<256, 256, 0, stream>>>(Wo, Wv, bv, bo, Wovb, bvo);
    k_cast_flat<<<1024, 256, 0, stream>>>(Wf1, Wf1b, 262144);
    k_cast_flat<<<512, 256, 0, stream>>>(Wf2, Wf2b, 131072);
    k_cast_flat<<<256, 256, 0, stream>>>(Wfp, Wfpb, 65536);
    k_cast_x<<<8192, 256, 0, stream>>>(x0, cat);
    k_cast_x<<<8192, 256, 0, stream>>>(x1, cat + 8192L * 512);

    // ---- adjacency softmax stats + materialize A01 / At10 ----
    k_rowlse<<<8192, 256, 0, stream>>>(adj, 2048, 4194304L, rlse);
    k_colpart<<<dim3(8, 16, 4), 256, 0, stream>>>(adj, 2048, 4194304L, pm, ps);
    k_colcomb<<<32, 256, 0, stream>>>(pm, ps, clse);
    k_mat<<<dim3(32, 32, 4), 256, 0, stream>>>(adj, rlse, clse, A01, A01 + 4L * 4194304);

    // ---- u = x @ Wov.T + bvo (merged 16384 rows), then transpose slab-swapped ----
    gemm_bt<<<dim3(128, 2, 1), 256, 0, stream>>>(cat, 0L, 512, Wovb, 0L, 256, 256, 2, EpiOut{ubuf, bvo, 1.f});
    k_tr<<<dim3(4, 32, 8), 256, 0, stream>>>(ubuf, ut);

    // ---- m = [A01;At10] @ ut (8 merged batches), split-K ----
    if (ks_m > 1) {
        gemm_bt<<<dim3(16, 2 * ks_m, 8), 256, 0, stream>>>(A01, 4194304L, 2048, ut, 524288L, 2048,
                                                           2048 / ks_m, 2, EpiPart{part, 524288L, 4194304L});
        k_comb_m<<<4096, 256, 0, stream>>>(part, ks_m, cat);
    } else {
        gemm_bt<<<dim3(16, 2, 8), 256, 0, stream>>>(A01, 4194304L, 2048, ut, 524288L, 2048,
                                                    2048, 2, EpiCat{cat});
    }

    // ---- h = cat @ Wf1.T + bf1 (merged) ----
    gemm_bt<<<dim3(128, 4, 1), 256, 0, stream>>>(cat, 0L, 512, Wf1b, 0L, 512, 512, 4, EpiH{hbuf, bf1});
    k_ln<<<16384, 256, 0, stream>>>(hbuf, lng, lnb, gbuf);

    // ---- d = x + g @ Wf2.T + bf2 (merged, split-K) ----
    if (ks_d > 1) {
        gemm_bt<<<dim3(128, 2 * ks_d, 1), 256, 0, stream>>>(gbuf, 0L, 512, Wf2b, 0L, 512,
                                                            512 / ks_d, 2, EpiPart{part, 0L, 4194304L});
        k_comb_d<<<4096, 256, 0, stream>>>(part, ks_d, bf2, x0, x1, dbuf);
    } else {
        gemm_bt<<<dim3(128, 2, 1), 256, 0, stream>>>(gbuf, 0L, 512, Wf2b, 0L, 512, 512, 2,
                                                     EpiD{dbuf, bf2, x0, x1});
    }

    // ---- z / log_sigmoid (merged 16384 rows) ----
    k_z<<<4096, 256, 0, stream>>>(dbuf, Wz, bz, lszp, lszn);

    // ---- md = (d @ Wfp.T + bfp)/4 (merged) ----
    gemm_bt<<<dim3(128, 2, 1), 256, 0, stream>>>(dbuf, 0L, 256, Wfpb, 0L, 256, 256, 2, EpiOut{mdb, bfp, 0.25f});

    // ---- sim = md0 @ md1^T -> scores area (ld 2049) ----
    gemm_bt<<<dim3(16, 16, 4), 256, 0, stream>>>(mdb, 524288L, 256, mdb + 4L * 524288, 524288L, 256,
                                                 256, 16, EpiSim{scores});

    // ---- log-softmax stats + fused col argmax over sim ----
    k_rowlse<<<8192, 256, 0, stream>>>(scores, 2049, 4198401L, rowLSE);
    k_colstat<<<dim3(8, 16, 4), 256, 0, stream>>>(scores, rowLSE, lszp, pm, ps, pcv, pci);
    k_colcomb<<<32, 256, 0, stream>>>(pm, ps, colLSE);

    // ---- in-place inner + row argmax + borders ----
    k_scores<<<8192, 256, 0, stream>>>(scores, rowLSE, colLSE, lszp, lszn, rmax, ridx);
    k_colmaxB<<<32, 256, 0, stream>>>(pcv, pci, lszn, scores, cidx);

    // ---- mutual matching ----
    k_match0<<<32, 256, 0, stream>>>(ridx, cidx, rmax, out_m0, out_ms0, ms0ws, v0ws);
    k_match1<<<32, 256, 0, stream>>>(cidx, ridx, ms0ws, v0ws, out_m1, out_ms1);
}

// Round 3
// 578.117 us; speedup vs baseline: 1.7843x; 1.1842x over previous
//
#include <hip/hip_runtime.h>

typedef unsigned short ushort_t;
typedef __bf16 bf16x8 __attribute__((ext_vector_type(8)));
typedef float f32x4 __attribute__((ext_vector_type(4)));

__device__ __forceinline__ ushort_t f2bf(float f) {
    unsigned int u = __float_as_uint(f);
    unsigned int r = (u + 0x7fffu + ((u >> 16) & 1u)) >> 16;
    return (ushort_t)r;
}
__device__ __forceinline__ float bf2f(ushort_t u) {
    return __uint_as_float(((unsigned int)u) << 16);
}
__device__ __forceinline__ float wredsum(float v) {
    for (int o = 32; o; o >>= 1) v += __shfl_xor(v, o, 64);
    return v;
}
__device__ __forceinline__ float wredmax(float v) {
    for (int o = 32; o; o >>= 1) v = fmaxf(v, __shfl_xor(v, o, 64));
    return v;
}
__device__ __forceinline__ float logsig(float z) {
    return (z >= 0.f) ? -log1pf(expf(-z)) : (z - log1pf(expf(z)));
}
// online (max, sumexp) merge
__device__ __forceinline__ void msmerge(float& m, float& s, float om, float os) {
    float M = fmaxf(m, om);
    s = s * __expf(m - M) + os * __expf(om - M);
    m = M;
}

// ---------------- weight prep: Wov = Wo @ Wv, bvo = Wo@bv + bo ----------------
__global__ void k_wov(const float* __restrict__ Wo, const float* __restrict__ Wv,
                      const float* __restrict__ bvv, const float* __restrict__ bo,
                      ushort_t* __restrict__ Wovb, float* __restrict__ bvo) {
    int o = blockIdx.x, k = threadIdx.x;
    float s = 0.f;
    for (int j = 0; j < 256; ++j) s += Wo[o * 256 + j] * Wv[j * 256 + k];
    Wovb[o * 256 + k] = f2bf(s);
    float pb = Wo[o * 256 + k] * bvv[k];
    pb = wredsum(pb);
    __shared__ float sh[4];
    if ((k & 63) == 0) sh[k >> 6] = pb;
    __syncthreads();
    if (k == 0) bvo[o] = sh[0] + sh[1] + sh[2] + sh[3] + bo[o];
}

__global__ void k_cast_flat(const float* __restrict__ src, ushort_t* __restrict__ dst, int n) {
    int i = blockIdx.x * 256 + threadIdx.x;
    if (i < n) dst[i] = f2bf(src[i]);
}

// x (R,256) fp32 -> cat (R,512) bf16 at cols [0,256)
__global__ void k_cast_x(const float* __restrict__ src, ushort_t* __restrict__ dst) {
    long i = (long)blockIdx.x * 256 + threadIdx.x;
    long r = i >> 8;
    int c = (int)(i & 255);
    dst[r * 512 + c] = f2bf(src[i]);
}

// ---------------- fused adj pass: raw-transpose bf16 + row/col LSE partials ----------------
// grid (32 n-tiles, 32 m-tiles, 4)
__global__ void k_prep(const float* __restrict__ adj, ushort_t* __restrict__ At10,
                       float* __restrict__ rowm, float* __restrict__ rows_,
                       float* __restrict__ colm, float* __restrict__ cols_) {
    int b = blockIdx.z;
    int n0 = blockIdx.x * 64, m0 = blockIdx.y * 64;
    __shared__ ushort_t T[64][72];
    int t = threadIdx.x;
    int r16 = t >> 4, cq = t & 15;
    const float* base = adj + ((long)b * 2048 + m0) * 2048 + n0;
#pragma unroll
    for (int p = 0; p < 4; ++p) {
        int row = p * 16 + r16;
        float4 v = *(const float4*)(base + (long)row * 2048 + cq * 4);
        // row-LSE partial over this thread's 4 values
        float m = v.x, s = 1.f;
        msmerge(m, s, v.y, 1.f);
        msmerge(m, s, v.z, 1.f);
        msmerge(m, s, v.w, 1.f);
        for (int o = 1; o < 16; o <<= 1) {
            float om = __shfl_xor(m, o, 64);
            float os = __shfl_xor(s, o, 64);
            msmerge(m, s, om, os);
        }
        if (cq == 0) {
            int idx = (b * 32 + blockIdx.x) * 2048 + m0 + row;
            rowm[idx] = m; rows_[idx] = s;
        }
        T[cq * 4 + 0][row] = f2bf(v.x);
        T[cq * 4 + 1][row] = f2bf(v.y);
        T[cq * 4 + 2][row] = f2bf(v.z);
        T[cq * 4 + 3][row] = f2bf(v.w);
    }
    __syncthreads();
#pragma unroll
    for (int p = 0; p < 4; ++p) {
        int rn = p * 16 + r16;
        float v0 = bf2f(T[rn][cq * 4 + 0]);
        float v1 = bf2f(T[rn][cq * 4 + 1]);
        float v2 = bf2f(T[rn][cq * 4 + 2]);
        float v3 = bf2f(T[rn][cq * 4 + 3]);
        uint2 o;
        o.x = (unsigned)T[rn][cq * 4 + 0] | ((unsigned)T[rn][cq * 4 + 1] << 16);
        o.y = (unsigned)T[rn][cq * 4 + 2] | ((unsigned)T[rn][cq * 4 + 3] << 16);
        *(uint2*)&At10[((long)b * 2048 + n0 + rn) * 2048 + m0 + cq * 4] = o;
        float m = v0, s = 1.f;
        msmerge(m, s, v1, 1.f);
        msmerge(m, s, v2, 1.f);
        msmerge(m, s, v3, 1.f);
        for (int o2 = 1; o2 < 16; o2 <<= 1) {
            float om = __shfl_xor(m, o2, 64);
            float os = __shfl_xor(s, o2, 64);
            msmerge(m, s, om, os);
        }
        if (cq == 0) {
            int idx = (b * 32 + blockIdx.y) * 2048 + n0 + rn;
            colm[idx] = m; cols_[idx] = s;
        }
    }
}

// combine nch chunk partials -> LSE per (b, n) ; grid 32 x 256
__global__ void k_statcomb(const float* __restrict__ pm, const float* __restrict__ ps,
                           int nch, float* __restrict__ out) {
    int idx = blockIdx.x * 256 + threadIdx.x;  // 8192
    int b = idx >> 11, n = idx & 2047;
    float mx = -3.4e38f;
    for (int c = 0; c < nch; ++c) mx = fmaxf(mx, pm[(b * nch + c) * 2048 + n]);
    float s = 0.f;
    for (int c = 0; c < nch; ++c) s += ps[(b * nch + c) * 2048 + n] * __expf(pm[(b * nch + c) * 2048 + n] - mx);
    out[idx] = mx + logf(s);
}

// ---------------- bf16 transpose of 8 slabs (2048,256)->(256,2048); dst slab = src^4 ----------------
__global__ void k_tr(const ushort_t* __restrict__ src, ushort_t* __restrict__ dst) {
    int z = blockIdx.z;
    int c0 = blockIdx.x * 64, r0 = blockIdx.y * 64;
    const ushort_t* s = src + (long)z * 524288;
    ushort_t* d = dst + (long)(z ^ 4) * 524288;
    __shared__ ushort_t T[64][68];
    int t = threadIdx.x;
    int ir = t >> 4, jc = t & 15;
#pragma unroll
    for (int p = 0; p < 4; ++p) {
        int row = p * 16 + ir;
        uint2 v = *(const uint2*)&s[(long)(r0 + row) * 256 + c0 + jc * 4];
        T[jc * 4 + 0][row] = (ushort_t)(v.x & 0xffff);
        T[jc * 4 + 1][row] = (ushort_t)(v.x >> 16);
        T[jc * 4 + 2][row] = (ushort_t)(v.y & 0xffff);
        T[jc * 4 + 3][row] = (ushort_t)(v.y >> 16);
    }
    __syncthreads();
#pragma unroll
    for (int p = 0; p < 4; ++p) {
        int crow = p * 16 + ir;
        uint2 o;
        o.x = (unsigned)T[crow][jc * 4 + 0] | ((unsigned)T[crow][jc * 4 + 1] << 16);
        o.y = (unsigned)T[crow][jc * 4 + 2] | ((unsigned)T[crow][jc * 4 + 3] << 16);
        *(uint2*)&d[(long)(c0 + crow) * 2048 + r0 + jc * 4] = o;
    }
}

// ---------------- gemm64: 64x64 tile, 4 waves 2x2 of 32x32, no batch ----------------
template <class Epi>
__global__ __launch_bounds__(256, 4) void gemm64(const ushort_t* __restrict__ A, int lda,
                                                 const ushort_t* __restrict__ Bt, int ldb,
                                                 int K, Epi epi) {
    __shared__ ushort_t lA[8 * 66 * 8];
    __shared__ ushort_t lB[8 * 66 * 8];
    const int m0 = blockIdx.x * 64, n0 = blockIdx.y * 64;
    const int t = threadIdx.x;
    const int lane = t & 63, wave = t >> 6;
    const int wm = (wave & 1) * 32, wn = (wave >> 1) * 32;
    const int q = lane >> 4, lm = lane & 15;
    const int r0 = t >> 3, kc = t & 7;
    const int r1 = 32 + r0;
    const int4* pa0 = (const int4*)(A + (long)(m0 + r0) * lda + kc * 8);
    const int4* pa1 = (const int4*)(A + (long)(m0 + r1) * lda + kc * 8);
    const int4* pb0 = (const int4*)(Bt + (long)(n0 + r0) * ldb + kc * 8);
    const int4* pb1 = (const int4*)(Bt + (long)(n0 + r1) * ldb + kc * 8);
    f32x4 zero = {0.f, 0.f, 0.f, 0.f};
    f32x4 acc[2][2];
    acc[0][0] = zero; acc[0][1] = zero; acc[1][0] = zero; acc[1][1] = zero;
    int4 ra0 = pa0[0], ra1 = pa1[0], rb0 = pb0[0], rb1 = pb1[0];
    const int nkt = K >> 6;
    for (int kt = 0; kt < nkt; ++kt) {
        __syncthreads();
        *(int4*)&lA[(kc * 66 + r0) * 8] = ra0;
        *(int4*)&lA[(kc * 66 + r1) * 8] = ra1;
        *(int4*)&lB[(kc * 66 + r0) * 8] = rb0;
        *(int4*)&lB[(kc * 66 + r1) * 8] = rb1;
        __syncthreads();
        if (kt + 1 < nkt) {
            ra0 = pa0[(kt + 1) * 8]; ra1 = pa1[(kt + 1) * 8];
            rb0 = pb0[(kt + 1) * 8]; rb1 = pb1[(kt + 1) * 8];
        }
#pragma unroll
        for (int kk = 0; kk < 2; ++kk) {
            bf16x8 af[2], bfr[2];
#pragma unroll
            for (int mi = 0; mi < 2; ++mi)
                af[mi] = *(const bf16x8*)&lA[((kk * 4 + q) * 66 + wm + mi * 16 + lm) * 8];
#pragma unroll
            for (int ni = 0; ni < 2; ++ni)
                bfr[ni] = *(const bf16x8*)&lB[((kk * 4 + q) * 66 + wn + ni * 16 + lm) * 8];
#pragma unroll
            for (int mi = 0; mi < 2; ++mi)
#pragma unroll
                for (int ni = 0; ni < 2; ++ni)
                    acc[mi][ni] = __builtin_amdgcn_mfma_f32_16x16x32_bf16(af[mi], bfr[ni], acc[mi][ni], 0, 0, 0);
        }
    }
#pragma unroll
    for (int mi = 0; mi < 2; ++mi)
#pragma unroll
        for (int ni = 0; ni < 2; ++ni)
#pragma unroll
            for (int r2 = 0; r2 < 4; ++r2) {
                int row = m0 + wm + mi * 16 + q * 4 + r2;
                int col = n0 + wn + ni * 16 + lm;
                epi(row, col, acc[mi][ni][r2]);
            }
}

struct GeU {  // bf16 = v + bias, ld 256
    ushort_t* dst; const float* bias;
    __device__ void operator()(int r, int c, float v) const {
        dst[(long)r * 256 + c] = f2bf(v + bias[c]);
    }
};
struct GeH {  // fp32 + bias, ld 512
    float* dst; const float* bias;
    __device__ void operator()(int r, int c, float v) const {
        dst[(long)r * 512 + c] = v + bias[c];
    }
};
struct GeD {  // bf16 = v + bias + resid
    ushort_t* dst; const float* bias; const float* x0; const float* x1;
    __device__ void operator()(int r, int c, float v) const {
        float rx = (r < 8192) ? x0[(long)r * 256 + c] : x1[(long)(r - 8192) * 256 + c];
        dst[(long)r * 256 + c] = f2bf(v + bias[c] + rx);
    }
};
struct GeMd {  // bf16 = (v+bias)*0.25
    ushort_t* dst; const float* bias;
    __device__ void operator()(int r, int c, float v) const {
        dst[(long)r * 256 + c] = f2bf((v + bias[c]) * 0.25f);
    }
};

// ---------------- fused m-GEMM: softmax(adj) @ u, both directions ----------------
// grid (32 m-tiles, 2 k-slices, 8): z<4 -> m0 (fp32 adj + rlse), z>=4 -> m1 (bf16 adjT + clse)
// block tile 64 rows x 256 d; 4 waves along d; Kslice=1024, BK=64.
__global__ __launch_bounds__(256, 2) void gemm_madj(
    const float* __restrict__ adj, const ushort_t* __restrict__ At10,
    const ushort_t* __restrict__ ut, const float* __restrict__ rlse,
    const float* __restrict__ clse, float* __restrict__ part, int Kslice) {
    __shared__ ushort_t lA[8 * 66 * 8];
    __shared__ ushort_t lB[8 * 258 * 8];
    const int z = blockIdx.z, b = z & 3, side = z >> 2;
    const int m0 = blockIdx.x * 64;
    const int slice = blockIdx.y;
    const int kbase = slice * Kslice;
    const int t = threadIdx.x;
    const int lane = t & 63, wave = t >> 6;
    const int q = lane >> 4, lm = lane & 15;
    const float* rs = (side == 0 ? rlse : clse) + b * 2048 + m0;
    // B staging: 8 int4/thread
    const int bd = t >> 3, bkc = t & 7;
    const int4* pb[8];
#pragma unroll
    for (int i = 0; i < 8; ++i)
        pb[i] = (const int4*)(ut + (long)z * 524288 + (long)(i * 32 + bd) * 2048 + kbase + bkc * 8);
    // A m0: 4 float4/thread ; A m1: 2 int4/thread
    const int ar = t >> 4, ac4 = t & 15;       // m0: row part, float4 col
    const float* paf[4];
    float rlf[4];
#pragma unroll
    for (int i = 0; i < 4; ++i) {
        paf[i] = adj + ((long)(b * 2048 + m0 + i * 16 + ar)) * 2048 + kbase + ac4 * 4;
        rlf[i] = rs[i * 16 + ar];
    }
    const int tr0 = t >> 3, tkc = t & 7;       // m1 rows
    const int4* pat[2];
    float rlt[2];
#pragma unroll
    for (int i = 0; i < 2; ++i) {
        pat[i] = (const int4*)(At10 + ((long)(b * 2048 + m0 + i * 32 + tr0)) * 2048 + kbase + tkc * 8);
        rlt[i] = rs[i * 32 + tr0];
    }
    f32x4 zero = {0.f, 0.f, 0.f, 0.f};
    f32x4 acc[4][4];
#pragma unroll
    for (int mi = 0; mi < 4; ++mi)
#pragma unroll
        for (int ni = 0; ni < 4; ++ni) acc[mi][ni] = zero;

    int4 rb[8];
#pragma unroll
    for (int i = 0; i < 8; ++i) rb[i] = pb[i][0];
    float4 raf[4];
    int4 rat[2];
    if (side == 0) {
#pragma unroll
        for (int i = 0; i < 4; ++i) raf[i] = *(const float4*)(paf[i]);
    } else {
#pragma unroll
        for (int i = 0; i < 2; ++i) rat[i] = pat[i][0];
    }
    const int nkt = Kslice >> 6;
    for (int kt = 0; kt < nkt; ++kt) {
        __syncthreads();
#pragma unroll
        for (int i = 0; i < 8; ++i) *(int4*)&lB[(bkc * 258 + i * 32 + bd) * 8] = rb[i];
        if (side == 0) {
#pragma unroll
            for (int i = 0; i < 4; ++i) {
                float4 v = raf[i];
                float rl = rlf[i];
                uint2 o;
                o.x = (unsigned)f2bf(__expf(v.x - rl)) | ((unsigned)f2bf(__expf(v.y - rl)) << 16);
                o.y = (unsigned)f2bf(__expf(v.z - rl)) | ((unsigned)f2bf(__expf(v.w - rl)) << 16);
                *(uint2*)&lA[((ac4 >> 1) * 66 + i * 16 + ar) * 8 + (ac4 & 1) * 4] = o;
            }
        } else {
#pragma unroll
            for (int i = 0; i < 2; ++i) {
                int4 w = rat[i];
                float rl = rlt[i];
                unsigned u[4] = {(unsigned)w.x, (unsigned)w.y, (unsigned)w.z, (unsigned)w.w};
                uint2 o0, o1;
                o0.x = (unsigned)f2bf(__expf(bf2f((ushort_t)(u[0] & 0xffff)) - rl)) |
                       ((unsigned)f2bf(__expf(bf2f((ushort_t)(u[0] >> 16)) - rl)) << 16);
                o0.y = (unsigned)f2bf(__expf(bf2f((ushort_t)(u[1] & 0xffff)) - rl)) |
                       ((unsigned)f2bf(__expf(bf2f((ushort_t)(u[1] >> 16)) - rl)) << 16);
                o1.x = (unsigned)f2bf(__expf(bf2f((ushort_t)(u[2] & 0xffff)) - rl)) |
                       ((unsigned)f2bf(__expf(bf2f((ushort_t)(u[2] >> 16)) - rl)) << 16);
                o1.y = (unsigned)f2bf(__expf(bf2f((ushort_t)(u[3] & 0xffff)) - rl)) |
                       ((unsigned)f2bf(__expf(bf2f((ushort_t)(u[3] >> 16)) - rl)) << 16);
                *(uint2*)&lA[(tkc * 66 + i * 32 + tr0) * 8] = o0;
                *(uint2*)&lA[(tkc * 66 + i * 32 + tr0) * 8 + 4] = o1;
            }
        }
        __syncthreads();
        if (kt + 1 < nkt) {
#pragma unroll
            for (int i = 0; i < 8; ++i) rb[i] = pb[i][(kt + 1) * 8];
            if (side == 0) {
#pragma unroll
                for (int i = 0; i < 4; ++i) raf[i] = *(const float4*)(paf[i] + (kt + 1) * 64);
            } else {
#pragma unroll
                for (int i = 0; i < 2; ++i) rat[i] = pat[i][(kt + 1) * 8];
            }
        }
#pragma unroll
        for (int kk = 0; kk < 2; ++kk) {
            bf16x8 af[4], bfr[4];
#pragma unroll
            for (int mi = 0; mi < 4; ++mi)
                af[mi] = *(const bf16x8*)&lA[((kk * 4 + q) * 66 + mi * 16 + lm) * 8];
#pragma unroll
            for (int ni = 0; ni < 4; ++ni)
                bfr[ni] = *(const bf16x8*)&lB[((kk * 4 + q) * 258 + wave * 64 + ni * 16 + lm) * 8];
#pragma unroll
            for (int mi = 0; mi < 4; ++mi)
#pragma unroll
                for (int ni = 0; ni < 4; ++ni)
                    acc[mi][ni] = __builtin_amdgcn_mfma_f32_16x16x32_bf16(af[mi], bfr[ni], acc[mi][ni], 0, 0, 0);
        }
    }
#pragma unroll
    for (int mi = 0; mi < 4; ++mi)
#pragma unroll
        for (int ni = 0; ni < 4; ++ni)
#pragma unroll
            for (int r2 = 0; r2 < 4; ++r2) {
                int row = m0 + mi * 16 + q * 4 + r2;
                int col = wave * 64 + ni * 16 + lm;
                part[(long)slice * 4194304 + (long)z * 524288 + (long)row * 256 + col] = acc[mi][ni][r2];
            }
}

__global__ void k_comb_m(const float* __restrict__ mp, int ks, ushort_t* __restrict__ cat) {
    long e = ((long)blockIdx.x * 256 + threadIdx.x) * 4;  // total 8*2048*256
    float4 s = *(const float4*)(mp + e);
    for (int sl = 1; sl < ks; ++sl) {
        float4 tv = *(const float4*)(mp + (long)sl * 4194304 + e);
        s.x += tv.x; s.y += tv.y; s.z += tv.z; s.w += tv.w;
    }
    long row = e >> 8;
    int c = (int)(e & 255);
    uint2 o;
    o.x = (unsigned)f2bf(s.x) | ((unsigned)f2bf(s.y) << 16);
    o.y = (unsigned)f2bf(s.z) | ((unsigned)f2bf(s.w) << 16);
    *(uint2*)&cat[row * 512 + 256 + c] = o;
}

// ---------------- 128-tile GEMM kept for sim ----------------
template <class Epi>
__global__ __launch_bounds__(256, 2) void gemm_bt(const ushort_t* __restrict__ A, long sA, int lda,
                                                  const ushort_t* __restrict__ Bt, long sB, int ldb,
                                                  int Kslice, int ntn, Epi epi) {
    __shared__ ushort_t lA[8 * 130 * 8];
    __shared__ ushort_t lB[8 * 130 * 8];
    const int b = blockIdx.z;
    const int nt = blockIdx.y % ntn, slice = blockIdx.y / ntn;
    const int m0 = blockIdx.x * 128, n0 = nt * 128;
    const int kbase = slice * Kslice;
    const ushort_t* Ab = A + (long)b * sA;
    const ushort_t* Bb = Bt + (long)b * sB;
    const int t = threadIdx.x;
    const int lane = t & 63, wave = t >> 6;
    const int wm = (wave & 1) * 64, wn = (wave >> 1) * 64;
    const int q = lane >> 4, lm = lane & 15;
    const int4* pa[4];
    const int4* pb[4];
    int arow[4], akc[4];
#pragma unroll
    for (int i = 0; i < 4; ++i) {
        int c = i * 256 + t;
        arow[i] = c >> 3;
        akc[i] = c & 7;
        pa[i] = (const int4*)(Ab + (long)(m0 + arow[i]) * lda + kbase + akc[i] * 8);
        pb[i] = (const int4*)(Bb + (long)(n0 + arow[i]) * ldb + kbase + akc[i] * 8);
    }
    f32x4 zero = {0.f, 0.f, 0.f, 0.f};
    f32x4 acc[4][4];
#pragma unroll
    for (int mi = 0; mi < 4; ++mi)
#pragma unroll
        for (int ni = 0; ni < 4; ++ni) acc[mi][ni] = zero;
    int4 ra[4], rb[4];
#pragma unroll
    for (int i = 0; i < 4; ++i) { ra[i] = pa[i][0]; rb[i] = pb[i][0]; }
    const int nkt = Kslice >> 6;
    for (int kt = 0; kt < nkt; ++kt) {
        __syncthreads();
#pragma unroll
        for (int i = 0; i < 4; ++i) {
            *(int4*)&lA[(akc[i] * 130 + arow[i]) * 8] = ra[i];
            *(int4*)&lB[(akc[i] * 130 + arow[i]) * 8] = rb[i];
        }
        __syncthreads();
        if (kt + 1 < nkt) {
#pragma unroll
            for (int i = 0; i < 4; ++i) { ra[i] = pa[i][(kt + 1) * 8]; rb[i] = pb[i][(kt + 1) * 8]; }
        }
#pragma unroll
        for (int kk = 0; kk < 2; ++kk) {
            bf16x8 af[4], bfr[4];
#pragma unroll
            for (int mi = 0; mi < 4; ++mi)
                af[mi] = *(const bf16x8*)&lA[((kk * 4 + q) * 130 + wm + mi * 16 + lm) * 8];
#pragma unroll
            for (int ni = 0; ni < 4; ++ni)
                bfr[ni] = *(const bf16x8*)&lB[((kk * 4 + q) * 130 + wn + ni * 16 + lm) * 8];
#pragma unroll
            for (int mi = 0; mi < 4; ++mi)
#pragma unroll
                for (int ni = 0; ni < 4; ++ni)
                    acc[mi][ni] = __builtin_amdgcn_mfma_f32_16x16x32_bf16(af[mi], bfr[ni], acc[mi][ni], 0, 0, 0);
        }
    }
#pragma unroll
    for (int mi = 0; mi < 4; ++mi)
#pragma unroll
        for (int ni = 0; ni < 4; ++ni)
#pragma unroll
            for (int r2 = 0; r2 < 4; ++r2) {
                int row = m0 + wm + mi * 16 + q * 4 + r2;
                int col = n0 + wn + ni * 16 + lm;
                epi(b, slice, row, col, acc[mi][ni][r2]);
            }
}

struct EpiSimB {  // bf16 into simb, ld 2048
    ushort_t* dst;
    __device__ void operator()(int b, int s, int r, int c, float v) const {
        dst[(long)b * 4194304 + (long)r * 2048 + c] = f2bf(v);
    }
};

// ---------------- LN + GELU (rows of 512) ----------------
__global__ void k_ln(const float* __restrict__ h, const float* __restrict__ lng,
                     const float* __restrict__ lnb, ushort_t* __restrict__ out) {
    int row = blockIdx.x;
    int t = threadIdx.x;
    const float* p = h + (long)row * 512;
    float a = p[t], c = p[t + 256];
    float s = wredsum(a + c);
    __shared__ float sh[4];
    if ((t & 63) == 0) sh[t >> 6] = s;
    __syncthreads();
    float mean = (sh[0] + sh[1] + sh[2] + sh[3]) * (1.f / 512.f);
    float da = a - mean, dc = c - mean;
    float s2 = wredsum(da * da + dc * dc);
    __shared__ float sh2[4];
    if ((t & 63) == 0) sh2[t >> 6] = s2;
    __syncthreads();
    float var = (sh2[0] + sh2[1] + sh2[2] + sh2[3]) * (1.f / 512.f);
    float inv = rsqrtf(var + 1e-5f);
    float x1 = da * inv * lng[t] + lnb[t];
    float x2 = dc * inv * lng[t + 256] + lnb[t + 256];
    float g1 = 0.5f * x1 * (1.f + erff(x1 * 0.70710678118654752f));
    float g2 = 0.5f * x2 * (1.f + erff(x2 * 0.70710678118654752f));
    out[(long)row * 512 + t] = f2bf(g1);
    out[(long)row * 512 + t + 256] = f2bf(g2);
}

// ---------------- z = d @ Wz + bz -> log_sigmoid(+-z); 16384 merged rows ----------------
__global__ void k_z(const ushort_t* __restrict__ dmat, const float* __restrict__ Wz,
                    const float* __restrict__ bzp, float* __restrict__ lszp,
                    float* __restrict__ lszn) {
    int row = blockIdx.x * 4 + (threadIdx.x >> 6);
    int l = threadIdx.x & 63;
    const ushort_t* p = dmat + (long)row * 256 + l * 4;
    float4 w = *(const float4*)(Wz + l * 4);
    float s = bf2f(p[0]) * w.x + bf2f(p[1]) * w.y + bf2f(p[2]) * w.z + bf2f(p[3]) * w.w;
    s = wredsum(s);
    if (l == 0) {
        float z = s + bzp[0];
        lszp[row] = logsig(z);
        lszn[row] = logsig(-z);
    }
}

// ---------------- sim row LSE (bf16) ----------------
__global__ void k_rowlse_b(const ushort_t* __restrict__ simb, float* __restrict__ out) {
    int blk = blockIdx.x;  // 8192
    const ushort_t* p = simb + (long)blk * 2048;
    int t = threadIdx.x;
    int4 w = *(const int4*)(p + t * 8);
    unsigned u[4] = {(unsigned)w.x, (unsigned)w.y, (unsigned)w.z, (unsigned)w.w};
    float v[8];
#pragma unroll
    for (int i = 0; i < 4; ++i) {
        v[i * 2] = bf2f((ushort_t)(u[i] & 0xffff));
        v[i * 2 + 1] = bf2f((ushort_t)(u[i] >> 16));
    }
    float mx = v[0];
#pragma unroll
    for (int i = 1; i < 8; ++i) mx = fmaxf(mx, v[i]);
    mx = wredmax(mx);
    __shared__ float sh[4];
    if ((t & 63) == 0) sh[t >> 6] = mx;
    __syncthreads();
    mx = fmaxf(fmaxf(sh[0], sh[1]), fmaxf(sh[2], sh[3]));
    float s = 0.f;
#pragma unroll
    for (int i = 0; i < 8; ++i) s += __expf(v[i] - mx);
    s = wredsum(s);
    __shared__ float sh2[4];
    if ((t & 63) == 0) sh2[t >> 6] = s;
    __syncthreads();
    if (t == 0) out[blk] = mx + logf(sh2[0] + sh2[1] + sh2[2] + sh2[3]);
}

// ---------------- fused sim col LSE partial + col argmax (bf16), 128-row chunks ----------------
__global__ void k_colstat_b(const ushort_t* __restrict__ simb, const float* __restrict__ rowLSE,
                            const float* __restrict__ lszp, float* __restrict__ pm,
                            float* __restrict__ ps, float* __restrict__ pcv,
                            int* __restrict__ pci) {
    int b = blockIdx.z;
    int n = blockIdx.x * 256 + threadIdx.x;
    int mstart = blockIdx.y * 128;
    const ushort_t* p = simb + (long)b * 4194304 + n;
    float mx = -3.4e38f, s = 0.f;
    float bv = -3.4e38f;
    int bi = 0;
    for (int mm = 0; mm < 128; ++mm) {
        int m = mstart + mm;
        float v = bf2f(p[(long)m * 2048]);
        if (v > mx) { s = s * __expf(mx - v) + 1.f; mx = v; }
        else s += __expf(v - mx);
        float tv = 2.f * v - rowLSE[b * 2048 + m] + lszp[b * 2048 + m];
        if (tv > bv) { bv = tv; bi = m; }
    }
    int idx = (b * 16 + blockIdx.y) * 2048 + n;
    pm[idx] = mx; ps[idx] = s;
    pcv[idx] = bv; pci[idx] = bi;
}

// ---------------- transform bf16 sim -> fp32 scores, row argmax, border col ----------------
__global__ void k_scores_b(const ushort_t* __restrict__ simb, float* __restrict__ scores,
                           const float* __restrict__ rowLSE, const float* __restrict__ colLSE,
                           const float* __restrict__ lszp, const float* __restrict__ lszn,
                           float* __restrict__ rmax, int* __restrict__ ridx) {
    int blk = blockIdx.x;
    int b = blk >> 11, m = blk & 2047;
    const ushort_t* src = simb + (long)blk * 2048;
    float* dst = scores + (long)b * 4198401 + (long)m * 2049;
    int t = threadIdx.x;
    float rl = rowLSE[blk], l0 = lszp[blk];
    const float* cl = colLSE + b * 2048;
    const float* l1 = lszp + 8192 + b * 2048;
    int n0 = t * 8;
    int4 w = *(const int4*)(src + n0);
    unsigned u[4] = {(unsigned)w.x, (unsigned)w.y, (unsigned)w.z, (unsigned)w.w};
    float bv = -3.4e38f;
    int bi = 0;
#pragma unroll
    for (int i = 0; i < 4; ++i) {
#pragma unroll
        for (int h = 0; h < 2; ++h) {
            int n = n0 + i * 2 + h;
            float sv = bf2f((ushort_t)(h ? (u[i] >> 16) : (u[i] & 0xffff)));
            float v = 2.f * sv - rl - cl[n] + l0 + l1[n];
            dst[n] = v;
            if (v > bv) { bv = v; bi = n; }
        }
    }
    for (int o = 32; o; o >>= 1) {
        float ov = __shfl_xor(bv, o, 64);
        int oi = __shfl_xor(bi, o, 64);
        if (ov > bv || (ov == bv && oi < bi)) { bv = ov; bi = oi; }
    }
    __shared__ float sv2[4];
    __shared__ int si2[4];
    if ((t & 63) == 0) { sv2[t >> 6] = bv; si2[t >> 6] = bi; }
    __syncthreads();
    if (t == 0) {
        for (int wv = 1; wv < 4; ++wv)
            if (sv2[wv] > bv || (sv2[wv] == bv && si2[wv] < bi)) { bv = sv2[wv]; bi = si2[wv]; }
        rmax[blk] = bv;
        ridx[blk] = bi;
        dst[2048] = lszn[blk];
    }
}

// ---------------- combine col argmax chunks, write border row + corner ----------------
__global__ void k_colmaxB(const float* __restrict__ pcv, const int* __restrict__ pci,
                          const float* __restrict__ lszn, float* __restrict__ scores,
                          int* __restrict__ cidx) {
    int idx = blockIdx.x * 256 + threadIdx.x;  // 8192
    int b = idx >> 11, n = idx & 2047;
    float bv = -3.4e38f;
    int bi = 0;
#pragma unroll
    for (int c = 0; c < 16; ++c) {
        float v = pcv[(b * 16 + c) * 2048 + n];
        int i = pci[(b * 16 + c) * 2048 + n];
        if (v > bv || (v == bv && i < bi)) { bv = v; bi = i; }
    }
    cidx[idx] = bi;
    scores[(long)b * 4198401 + 2048L * 2049 + n] = lszn[8192 + idx];
    if (n == 0) scores[(long)b * 4198401 + 2048L * 2049 + 2048] = 0.f;
}

__global__ void k_match0(const int* __restrict__ ridx, const int* __restrict__ cidx,
                         const float* __restrict__ rmax, float* __restrict__ m0out,
                         float* __restrict__ ms0out, float* __restrict__ ms0ws,
                         int* __restrict__ v0ws) {
    int idx = blockIdx.x * 256 + threadIdx.x;
    int b = idx >> 11, m = idx & 2047;
    int j = ridx[idx];
    bool mutual = (cidx[b * 2048 + j] == m);
    float e = mutual ? expf(rmax[idx]) : 0.f;
    bool valid = mutual && (e > 0.1f);
    m0out[idx] = valid ? (float)j : -1.f;
    ms0out[idx] = e;
    ms0ws[idx] = e;
    v0ws[idx] = valid ? 1 : 0;
}

__global__ void k_match1(const int* __restrict__ cidx, const int* __restrict__ ridx,
                         const float* __restrict__ ms0ws, const int* __restrict__ v0ws,
                         float* __restrict__ m1out, float* __restrict__ ms1out) {
    int idx = blockIdx.x * 256 + threadIdx.x;
    int b = idx >> 11, n = idx & 2047;
    int j = cidx[idx];
    bool mutual = (ridx[b * 2048 + j] == n);
    float ms1 = mutual ? ms0ws[b * 2048 + j] : 0.f;
    bool valid = mutual && (v0ws[b * 2048 + j] != 0);
    m1out[idx] = valid ? (float)j : -1.f;
    ms1out[idx] = ms1;
}

extern "C" void kernel_launch(void* const* d_in, const int* in_sizes, int n_in,
                              void* d_out, int out_size, void* d_ws, size_t ws_size,
                              hipStream_t stream) {
    (void)in_sizes; (void)n_in; (void)out_size; (void)ws_size;
    const float* x0  = (const float*)d_in[0];
    const float* x1  = (const float*)d_in[1];
    const float* adj = (const float*)d_in[2];
    const float* Wv  = (const float*)d_in[3];
    const float* bv  = (const float*)d_in[4];
    const float* Wo  = (const float*)d_in[5];
    const float* bo  = (const float*)d_in[6];
    const float* Wf1 = (const float*)d_in[7];
    const float* bf1 = (const float*)d_in[8];
    const float* lng = (const float*)d_in[9];
    const float* lnb = (const float*)d_in[10];
    const float* Wf2 = (const float*)d_in[11];
    const float* bf2 = (const float*)d_in[12];
    const float* Wfp = (const float*)d_in[13];
    const float* bfp = (const float*)d_in[14];
    const float* Wz  = (const float*)d_in[15];
    const float* bz  = (const float*)d_in[16];

    float* out = (float*)d_out;
    float* scores  = out;
    float* out_m0  = out + 16793604;
    float* out_m1  = out_m0 + 8192;
    float* out_ms0 = out_m1 + 8192;
    float* out_ms1 = out_ms0 + 8192;

    char* base = (char*)d_ws;
    // Region1 [0,32M): At10_raw (prep->madj), then hbuf (h-gemm->ln)
    ushort_t* At10 = (ushort_t*)base;
    float*    hbuf = (float*)base;
    // Region2 [32M,66M): part (madj->comb), then simb (sim->scores)
    float*    part = (float*)(base + 33554432);
    ushort_t* simb = (ushort_t*)(base + 33554432);
    size_t off = 67108864;
    auto alloc = [&](size_t sz) { char* p = base + off; off += (sz + 255) & ~(size_t)255; return p; };
    ushort_t* cat  = (ushort_t*)alloc(16777216);   // 16384x512 bf16
    ushort_t* ubuf = (ushort_t*)alloc(8388608);    // 16384x256 bf16
    ushort_t* ut   = (ushort_t*)alloc(8388608);    // 8 slabs 256x2048 (slab-swapped)
    ushort_t* gbuf = (ushort_t*)alloc(16777216);   // 16384x512 bf16
    ushort_t* dbuf = (ushort_t*)alloc(8388608);    // 16384x256 bf16
    ushort_t* mdb  = (ushort_t*)alloc(8388608);    // 16384x256 bf16
    ushort_t* Wovb = (ushort_t*)alloc(131072);
    ushort_t* Wf1b = (ushort_t*)alloc(524288);
    ushort_t* Wf2b = (ushort_t*)alloc(262144);
    ushort_t* Wfpb = (ushort_t*)alloc(131072);
    float* bvo     = (float*)alloc(1024);
    float* rowm    = (float*)alloc(1048576);
    float* rows_   = (float*)alloc(1048576);
    float* colm    = (float*)alloc(1048576);
    float* cols_   = (float*)alloc(1048576);
    float* rlse    = (float*)alloc(32768);
    float* clse    = (float*)alloc(32768);
    float* pm      = (float*)alloc(524288);
    float* ps      = (float*)alloc(524288);
    float* pcv     = (float*)alloc(524288);
    int*   pci     = (int*)alloc(524288);
    float* rowLSE  = (float*)alloc(32768);
    float* colLSE  = (float*)alloc(32768);
    float* rmax    = (float*)alloc(32768);
    int*   ridx    = (int*)alloc(32768);
    int*   cidx    = (int*)alloc(32768);
    float* lszp    = (float*)alloc(65536);
    float* lszn    = (float*)alloc(65536);
    float* ms0ws   = (float*)alloc(32768);
    int*   v0ws    = (int*)alloc(32768);

    // ---- weight prep + casts ----
    k_wov<<<256, 256, 0, stream>>>(Wo, Wv, bv, bo, Wovb, bvo);
    k_cast_flat<<<1024, 256, 0, stream>>>(Wf1, Wf1b, 262144);
    k_cast_flat<<<512, 256, 0, stream>>>(Wf2, Wf2b, 131072);
    k_cast_flat<<<256, 256, 0, stream>>>(Wfp, Wfpb, 65536);
    k_cast_x<<<8192, 256, 0, stream>>>(x0, cat);
    k_cast_x<<<8192, 256, 0, stream>>>(x1, cat + 8192L * 512);

    // ---- adjacency: raw transpose + fused LSE partials ----
    k_prep<<<dim3(32, 32, 4), 256, 0, stream>>>(adj, At10, rowm, rows_, colm, cols_);
    k_statcomb<<<32, 256, 0, stream>>>(rowm, rows_, 32, rlse);
    k_statcomb<<<32, 256, 0, stream>>>(colm, cols_, 32, clse);

    // ---- u = x @ Wov.T + bvo, then transpose slab-swapped ----
    gemm64<<<dim3(256, 4), 256, 0, stream>>>(cat, 512, Wovb, 256, 256, GeU{ubuf, bvo});
    k_tr<<<dim3(4, 32, 8), 256, 0, stream>>>(ubuf, ut);

    // ---- fused m = softmax(adj) @ u (both directions), split-K=2 ----
    gemm_madj<<<dim3(32, 2, 8), 256, 0, stream>>>(adj, At10, ut, rlse, clse, part, 1024);
    k_comb_m<<<4096, 256, 0, stream>>>(part, 2, cat);

    // ---- h = cat @ Wf1.T + bf1 ----
    gemm64<<<dim3(256, 8), 256, 0, stream>>>(cat, 512, Wf1b, 512, 512, GeH{hbuf, bf1});
    k_ln<<<16384, 256, 0, stream>>>(hbuf, lng, lnb, gbuf);

    // ---- d = x + g @ Wf2.T + bf2 ----
    gemm64<<<dim3(256, 4), 256, 0, stream>>>(gbuf, 512, Wf2b, 512, 512, GeD{dbuf, bf2, x0, x1});

    // ---- z / log_sigmoid ----
    k_z<<<4096, 256, 0, stream>>>(dbuf, Wz, bz, lszp, lszn);

    // ---- md = (d @ Wfp.T + bfp)/4 ----
    gemm64<<<dim3(256, 4), 256, 0, stream>>>(dbuf, 256, Wfpb, 256, 256, GeMd{mdb, bfp});

    // ---- sim = md0 @ md1^T -> bf16 simb ----
    gemm_bt<<<dim3(16, 16, 4), 256, 0, stream>>>(mdb, 524288L, 256, mdb + 4L * 524288, 524288L, 256,
                                                 256, 16, EpiSimB{simb});

    // ---- log-softmax stats + fused col argmax over sim ----
    k_rowlse_b<<<8192, 256, 0, stream>>>(simb, rowLSE);
    k_colstat_b<<<dim3(8, 16, 4), 256, 0, stream>>>(simb, rowLSE, lszp, pm, ps, pcv, pci);
    k_statcomb<<<32, 256, 0, stream>>>(pm, ps, 16, colLSE);

    // ---- transform + row argmax + borders ----
    k_scores_b<<<8192, 256, 0, stream>>>(simb, scores, rowLSE, colLSE, lszp, lszn, rmax, ridx);
    k_colmaxB<<<32, 256, 0, stream>>>(pcv, pci, lszn, scores, cidx);

    // ---- mutual matching ----
    k_match0<<<32, 256, 0, stream>>>(ridx, cidx, rmax, out_m0, out_ms0, ms0ws, v0ws);
    k_match1<<<32, 256, 0, stream>>>(cidx, ridx, ms0ws, v0ws, out_m1, out_ms1);
}